// Round 1
// 6491.920 us; speedup vs baseline: 1.2405x; 1.2405x over previous
//
#include <hip/hip_runtime.h>
#include <hip/hip_bf16.h>

#define D 100

typedef __hip_bfloat16 bf16;

__device__ __forceinline__ float ldf(const void* p, long long i, int f32) {
    return f32 ? ((const float*)p)[i] : __bfloat162float(((const bf16*)p)[i]);
}

__device__ __forceinline__ float b2f(unsigned short u) {
    return __uint_as_float(((unsigned int)u) << 16);
}

// ---------- input dtype detector: 0 = bf16, 1 = fp32 ----------
__global__ void detectk(const void* __restrict__ emb, int* __restrict__ flag)
{
    const unsigned short* u = (const unsigned short*)emb;
    __shared__ int cnt;
    if (threadIdx.x == 0) cnt = 0;
    __syncthreads();
    int good = 0;
    for (int i = threadIdx.x; i < 512; i += 256) {
        int e = (u[i] >> 7) & 0xFF;
        if (e >= 118 && e <= 137) good++;
    }
    atomicAdd(&cnt, good);
    __syncthreads();
    if (threadIdx.x == 0) *flag = (cnt >= 410) ? 0 : 1;
}

// ---------- input conversions ----------

__global__ void convw(const void* __restrict__ wi, const void* __restrict__ w1,
    const void* __restrict__ w2, const int* __restrict__ flag, float* __restrict__ Wf)
{
    int i = blockIdx.x * 256 + threadIdx.x;
    int f = *flag;
    if (i < 30000)      Wf[i] = ldf(wi, i, f);
    else if (i < 40000) Wf[i] = ldf(w1, i - 30000, f);
    else if (i < 50000) Wf[i] = ldf(w2, i - 40000, f);
}

// o0, o1 are FLOAT32 (output dtype follows the reference: jnp.float32).
__global__ void initk(const void* __restrict__ emb, const int* __restrict__ flag,
    bf16* __restrict__ x, float* __restrict__ o0, float* __restrict__ o1, int n)
{
    int i = blockIdx.x * 256 + threadIdx.x;
    if (i < n) {
        float v = ldf(emb, i, *flag);
        x[i] = __float2bfloat16(v);
        o0[i] = v;          // final[0] = raw embedding (scaled by 1/4 in fink)
        o1[i] = 0.0f;
    }
}

__global__ void fink(float* __restrict__ o0, float* __restrict__ o1, int nd)
{
    int i = blockIdx.x * 256 + threadIdx.x;
    if (i < nd) {
        o0[i] *= 0.25f;             // /(L+1)
        o1[i] *= (1.0f / 3.0f);     // /L
    }
}

// ---------- naive GEMM: Y[n,c] = sum_d X[n,d] * W[d,c] ----------

__global__ void mm_naive(const bf16* __restrict__ X, const float* __restrict__ W,
    bf16* __restrict__ Y, int n)
{
    long long t = (long long)blockIdx.x * 256 + threadIdx.x;
    if (t >= (long long)n * D) return;
    int nn = (int)(t / D), c = (int)(t - (long long)nn * D);
    const bf16* xr = X + (long long)nn * D;
    float acc = 0.f;
    for (int d = 0; d < D; ++d)
        acc = fmaf(__bfloat162float(xr[d]), W[d * D + c], acc);
    Y[t] = __float2bfloat16(acc);
}

// ---------- naive: Y = relu(X @ W + X) ----------

__global__ void mm_addrelu(const bf16* __restrict__ X, const float* __restrict__ W,
    bf16* __restrict__ Y, int n)
{
    long long t = (long long)blockIdx.x * 256 + threadIdx.x;
    if (t >= (long long)n * D) return;
    int nn = (int)(t / D), c = (int)(t - (long long)nn * D);
    const bf16* xr = X + (long long)nn * D;
    float acc = 0.f;
    for (int d = 0; d < D; ++d)
        acc = fmaf(__bfloat162float(xr[d]), W[d * D + c], acc);
    acc += __bfloat162float(xr[c]);
    Y[t] = __float2bfloat16(fmaxf(acc, 0.0f));
}

// ---------- COO SpMM half-pass p: S[r][dd] += v * X[c][p*50+dd] ----------

__global__ void coo_half(const int* __restrict__ rows, const int* __restrict__ cols,
    const void* __restrict__ vals, const int* __restrict__ flag,
    const bf16* __restrict__ X, float* __restrict__ S, int p, int n, int nnz)
{
    long long t = (long long)blockIdx.x * 256 + threadIdx.x;
    if (t >= (long long)nnz * 50) return;
    int e = (int)(t / 50), dd = (int)(t - (long long)e * 50);
    int r = rows[e], c = cols[e];
    if ((unsigned)r >= (unsigned)n || (unsigned)c >= (unsigned)n) return;
    float v = ldf(vals, e, *flag);
    atomicAdd(&S[(long long)r * 50 + dd],
              v * __bfloat162float(X[(long long)c * D + p * 50 + dd]));
}

__global__ void cvt_half(const float* __restrict__ S, bf16* __restrict__ X2, int p, int n)
{
    long long t = (long long)blockIdx.x * 256 + threadIdx.x;
    if (t >= (long long)n * 50) return;
    int nn = (int)(t / 50), dd = (int)(t - (long long)nn * 50);
    X2[(long long)nn * D + p * 50 + dd] = __float2bfloat16(S[t]);
}

// ---------- in-place row softmax on bf16 [n, D] ----------

__global__ void softmax_rows(bf16* __restrict__ L, int n)
{
    __shared__ float red[128];
    __shared__ float m_s, s_s;
    int r = blockIdx.x;
    if (r >= n) return;
    int d = threadIdx.x;
    float x = (d < D) ? __bfloat162float(L[(long long)r * D + d]) : -3.0e38f;
    red[d] = x; __syncthreads();
    for (int off = 64; off; off >>= 1) {
        if (d < off) red[d] = fmaxf(red[d], red[d + off]);
        __syncthreads();
    }
    if (d == 0) m_s = red[0];
    __syncthreads();
    float e = (d < D) ? __expf(x - m_s) : 0.0f;
    red[d] = e; __syncthreads();
    for (int off = 64; off; off >>= 1) {
        if (d < off) red[d] += red[d + off];
        __syncthreads();
    }
    if (d == 0) s_s = red[0];
    __syncthreads();
    if (d < D) L[(long long)r * D + d] = __float2bfloat16(e / s_s);
}

// ---------- hsm[k,d] = sum_n H1[n,k] * X2[n,d] ----------
// Split-K outer-product GEMM: each block owns a contiguous n-chunk, stages
// HSM_BATCH rows of H1 and X2 into LDS (fp32), 250 threads each accumulate a
// 4(k) x 10(d) register tile (40 independent FMAs per staged row), then one
// atomicAdd per element per block.
// Bank-conflict-free by construction: within a wave the distinct tk (resp td)
// values map to distinct banks; same-tk/td lanes broadcast.

#define HSM_G 500
#define HSM_BATCH 10

__global__ void hsm_outer(const bf16* __restrict__ H1, const bf16* __restrict__ X2,
    float* __restrict__ hsm, int n)
{
    __shared__ float sh[HSM_BATCH][D];   // H1 rows (k)
    __shared__ float sx[HSM_BATCH][D];   // X2 rows (d)
    const int t = threadIdx.x;
    const int tk = t / 10;               // 0..24 active (t < 250)
    const int td = t - tk * 10;          // 0..9

    float acc[4][10];
    #pragma unroll
    for (int i = 0; i < 4; ++i)
        #pragma unroll
        for (int j = 0; j < 10; ++j) acc[i][j] = 0.f;

    const int per = (n + HSM_G - 1) / HSM_G;     // 200 for n = 100000
    const int s = blockIdx.x * per;
    int e = s + per; if (e > n) e = n;

    for (int base = s; base < e; base += HSM_BATCH) {
        int cnt = e - base; if (cnt > HSM_BATCH) cnt = HSM_BATCH;
        __syncthreads();   // protect LDS of previous batch before overwrite
        // stage cnt rows of each array: cnt*25 ushort4 (8B) loads per array
        for (int v = t; v < cnt * 25; v += 256) {
            int r = v / 25, c4 = v - (v / 25) * 25;
            ushort4 h4 = *(const ushort4*)(H1 + (long long)(base + r) * D + 4 * c4);
            ushort4 x4 = *(const ushort4*)(X2 + (long long)(base + r) * D + 4 * c4);
            sh[r][4 * c4 + 0] = b2f(h4.x);
            sh[r][4 * c4 + 1] = b2f(h4.y);
            sh[r][4 * c4 + 2] = b2f(h4.z);
            sh[r][4 * c4 + 3] = b2f(h4.w);
            sx[r][4 * c4 + 0] = b2f(x4.x);
            sx[r][4 * c4 + 1] = b2f(x4.y);
            sx[r][4 * c4 + 2] = b2f(x4.z);
            sx[r][4 * c4 + 3] = b2f(x4.w);
        }
        __syncthreads();
        if (t < 250) {
            #pragma unroll
            for (int r = 0; r < HSM_BATCH; ++r) {
                if (r < cnt) {
                    float4 a = *(const float4*)&sh[r][tk * 4];
                    float b[10];
                    #pragma unroll
                    for (int j = 0; j < 10; ++j) b[j] = sx[r][td * 10 + j];
                    #pragma unroll
                    for (int j = 0; j < 10; ++j) {
                        acc[0][j] = fmaf(a.x, b[j], acc[0][j]);
                        acc[1][j] = fmaf(a.y, b[j], acc[1][j]);
                        acc[2][j] = fmaf(a.z, b[j], acc[2][j]);
                        acc[3][j] = fmaf(a.w, b[j], acc[3][j]);
                    }
                }
            }
        }
    }

    if (t < 250) {
        #pragma unroll
        for (int i = 0; i < 4; ++i)
            #pragma unroll
            for (int j = 0; j < 10; ++j)
                atomicAdd(&hsm[(tk * 4 + i) * D + td * 10 + j], acc[i][j]);
    }
}

// ---- finrow: x_new = hN + x2 (into X); o0 += l2n(x_new); o1 += l2n(hN) (fp32) ----

__global__ void finrow(const bf16* __restrict__ Hn, bf16* __restrict__ X,
    float* __restrict__ o0, float* __restrict__ o1, int n)
{
    __shared__ float red[128];
    __shared__ float ia_s, ib_s;
    int r = blockIdx.x;
    if (r >= n) return;
    int d = threadIdx.x;
    long long b = (long long)r * D;
    float hn = (d < D) ? __bfloat162float(Hn[b + d]) : 0.f;
    float x2 = (d < D) ? __bfloat162float(X[b + d]) : 0.f;
    float xn = hn + x2;
    red[d] = xn * xn; __syncthreads();
    for (int off = 64; off; off >>= 1) {
        if (d < off) red[d] += red[d + off];
        __syncthreads();
    }
    if (d == 0) ia_s = 1.0f / fmaxf(sqrtf(red[0]), 1e-12f);
    __syncthreads();
    red[d] = hn * hn; __syncthreads();
    for (int off = 64; off; off >>= 1) {
        if (d < off) red[d] += red[d + off];
        __syncthreads();
    }
    if (d == 0) ib_s = 1.0f / fmaxf(sqrtf(red[0]), 1e-12f);
    __syncthreads();
    if (d < D) {
        X[b + d] = __float2bfloat16(xn);
        o0[b + d] += xn * ia_s;
        o1[b + d] += hn * ib_s;
    }
}

// ---------- host ----------

extern "C" void kernel_launch(void* const* d_in, const int* in_sizes, int n_in,
                              void* d_out, int out_size, void* d_ws, size_t ws_size,
                              hipStream_t stream)
{
    const void* emb   = d_in[0];
    // d_in[1] = adj: cancels exactly in column-normalization (softmax rows sum to 1)
    const void* evals = d_in[2];
    const void* Wit   = d_in[3];
    const void* Wi1   = d_in[4];
    const void* Wi2   = d_in[5];
    const int* erows  = (const int*)d_in[6];
    const int* ecols  = (const int*)d_in[7];
    const int N   = in_sizes[0] / D;
    const int NNZ = in_sizes[2];
    const long long ND = (long long)N * D;

    float* o0 = (float*)d_out;      // item_embeddings accumulator (fp32 output!)
    float* o1 = o0 + ND;            // hs accumulator

    char* base = (char*)d_ws;
    size_t off = 0;
    auto alloc = [&](size_t bytes) -> void* {
        void* r = base + off;
        off += (bytes + 255) & ~(size_t)255;
        return r;
    };
    int*   flag = (int*)  alloc(256);
    float* hsm  = (float*)alloc(D * D * 4);
    float* Wf   = (float*)alloc(5 * D * D * 4);
    bf16*  B1   = (bf16*) alloc(ND * 2);
    bf16*  B2   = (bf16*) alloc(ND * 2);
    float* S20  = (float*)alloc((size_t)N * 50 * 4);
    bf16*  H1   = (bf16*)S20;   // alias: spmm scratch reused as H1 after cvt

    const int gND = (int)((ND + 255) / 256);
    const int gE  = (int)(((long long)NNZ * 50 + 255) / 256);
    const int gH  = (int)(((long long)N * 50 + 255) / 256);

    detectk<<<1, 256, 0, stream>>>(emb, flag);
    convw<<<(50000 + 255) / 256, 256, 0, stream>>>(Wit, Wi1, Wi2, flag, Wf);
    initk<<<gND, 256, 0, stream>>>(emb, flag, B1, o0, o1, (int)ND);

    for (int l = 0; l < 3; ++l) {
        mm_naive<<<gND, 256, 0, stream>>>(B1, Wf + l * 10000, B2, N);   // B2 = x@W
        for (int p = 0; p < 2; ++p) {                                   // B1 = A@B2
            hipMemsetAsync(S20, 0, (size_t)N * 50 * 4, stream);
            coo_half<<<gE, 256, 0, stream>>>(erows, ecols, evals, flag, B2, S20, p, N, NNZ);
            cvt_half<<<gH, 256, 0, stream>>>(S20, B1, p, N);
        }
        mm_addrelu<<<gND, 256, 0, stream>>>(B1, Wf + 30000, B2, N);     // B2 = relu(x2@W1+x2)
        mm_naive<<<gND, 256, 0, stream>>>(B2, Wf + 40000, H1, N);       // H1 = logits
        softmax_rows<<<N, 128, 0, stream>>>(H1, N);                     // H1 = softmax
        hipMemsetAsync(hsm, 0, D * D * 4, stream);
        hsm_outer<<<HSM_G, 256, 0, stream>>>(H1, B1, hsm, N);           // hsm = H1^T@x2
        mm_naive<<<gND, 256, 0, stream>>>(H1, hsm, B2, N);              // B2 = hN
        finrow<<<N, 128, 0, stream>>>(B2, B1, o0, o1, N);               // B1 = x_new; accum
    }
    fink<<<gND, 256, 0, stream>>>(o0, o1, (int)ND);
}

// Round 2
// 4518.111 us; speedup vs baseline: 1.7824x; 1.4369x over previous
//
#include <hip/hip_runtime.h>
#include <hip/hip_bf16.h>

#define D 100

typedef __hip_bfloat16 bf16;

__device__ __forceinline__ float ldf(const void* p, long long i, int f32) {
    return f32 ? ((const float*)p)[i] : __bfloat162float(((const bf16*)p)[i]);
}

__device__ __forceinline__ float b2f(unsigned short u) {
    return __uint_as_float(((unsigned int)u) << 16);
}

__device__ __forceinline__ unsigned short f2bu(float x) {
    union { bf16 b; unsigned short u; } cv;
    cv.b = __float2bfloat16(x);
    return cv.u;
}

// ---------- input dtype detector: 0 = bf16, 1 = fp32 ----------
__global__ void detectk(const void* __restrict__ emb, int* __restrict__ flag)
{
    const unsigned short* u = (const unsigned short*)emb;
    __shared__ int cnt;
    if (threadIdx.x == 0) cnt = 0;
    __syncthreads();
    int good = 0;
    for (int i = threadIdx.x; i < 512; i += 256) {
        int e = (u[i] >> 7) & 0xFF;
        if (e >= 118 && e <= 137) good++;
    }
    atomicAdd(&cnt, good);
    __syncthreads();
    if (threadIdx.x == 0) *flag = (cnt >= 410) ? 0 : 1;
}

// ---------- input conversions ----------

__global__ void convw(const void* __restrict__ wi, const void* __restrict__ w1,
    const void* __restrict__ w2, const int* __restrict__ flag, float* __restrict__ Wf)
{
    int i = blockIdx.x * 256 + threadIdx.x;
    int f = *flag;
    if (i < 30000)      Wf[i] = ldf(wi, i, f);
    else if (i < 40000) Wf[i] = ldf(w1, i - 30000, f);
    else if (i < 50000) Wf[i] = ldf(w2, i - 40000, f);
}

// o0, o1 are FLOAT32 (output dtype follows the reference: jnp.float32).
__global__ void initk(const void* __restrict__ emb, const int* __restrict__ flag,
    bf16* __restrict__ x, float* __restrict__ o0, float* __restrict__ o1, int n)
{
    int i = blockIdx.x * 256 + threadIdx.x;
    if (i < n) {
        float v = ldf(emb, i, *flag);
        x[i] = __float2bfloat16(v);
        o0[i] = v;          // final[0] = raw embedding (scaled by 1/4 in fink)
        o1[i] = 0.0f;
    }
}

__global__ void fink(float* __restrict__ o0, float* __restrict__ o1, int nd)
{
    int i = blockIdx.x * 256 + threadIdx.x;
    if (i < nd) {
        o0[i] *= 0.25f;             // /(L+1)
        o1[i] *= (1.0f / 3.0f);     // /L
    }
}

// ---------- naive GEMM: Y[n,c] = sum_d X[n,d] * W[d,c] ----------

__global__ void mm_naive(const bf16* __restrict__ X, const float* __restrict__ W,
    bf16* __restrict__ Y, int n)
{
    long long t = (long long)blockIdx.x * 256 + threadIdx.x;
    if (t >= (long long)n * D) return;
    int nn = (int)(t / D), c = (int)(t - (long long)nn * D);
    const bf16* xr = X + (long long)nn * D;
    float acc = 0.f;
    for (int d = 0; d < D; ++d)
        acc = fmaf(__bfloat162float(xr[d]), W[d * D + c], acc);
    Y[t] = __float2bfloat16(acc);
}

// ---------- naive: Y = relu(X @ W + X) ----------

__global__ void mm_addrelu(const bf16* __restrict__ X, const float* __restrict__ W,
    bf16* __restrict__ Y, int n)
{
    long long t = (long long)blockIdx.x * 256 + threadIdx.x;
    if (t >= (long long)n * D) return;
    int nn = (int)(t / D), c = (int)(t - (long long)nn * D);
    const bf16* xr = X + (long long)nn * D;
    float acc = 0.f;
    for (int d = 0; d < D; ++d)
        acc = fmaf(__bfloat162float(xr[d]), W[d * D + c], acc);
    acc += __bfloat162float(xr[c]);
    Y[t] = __float2bfloat16(fmaxf(acc, 0.0f));
}

// ---------- CSR construction (one-time; edge structure constant across layers) ----------

__global__ void hist(const int* __restrict__ rows, const int* __restrict__ cols,
    int* __restrict__ cnt, int n, int nnz)
{
    int e = blockIdx.x * 256 + threadIdx.x;
    if (e >= nnz) return;
    int r = rows[e], c = cols[e];
    if ((unsigned)r >= (unsigned)n || (unsigned)c >= (unsigned)n) return;
    atomicAdd(&cnt[r], 1);
}

// scan1: per-block (2048 elems) inclusive scan of cnt into offs[i+1]; block sums to bsum
__global__ void scan1(const int* __restrict__ cnt, int* __restrict__ offs,
    int* __restrict__ bsum, int n)
{
    __shared__ int sh[256];
    int b = blockIdx.x, t = threadIdx.x;
    int base = b * 2048 + t * 8;
    int v[8];
    int s = 0;
    #pragma unroll
    for (int i = 0; i < 8; ++i) {
        int idx = base + i;
        v[i] = (idx < n) ? cnt[idx] : 0;
        s += v[i];
    }
    sh[t] = s; __syncthreads();
    for (int off = 1; off < 256; off <<= 1) {
        int x = (t >= off) ? sh[t - off] : 0;
        __syncthreads();
        sh[t] += x;
        __syncthreads();
    }
    int run = sh[t] - s;   // exclusive prefix of this thread's chunk
    #pragma unroll
    for (int i = 0; i < 8; ++i) {
        run += v[i];
        int idx = base + i;
        if (idx < n) offs[idx + 1] = run;
    }
    if (t == 255) bsum[b] = sh[255];
}

// scan2: single block, exclusive scan of block sums (nb <= 256)
__global__ void scan2(int* __restrict__ bsum, int nb)
{
    __shared__ int sh[256];
    int t = threadIdx.x;
    int v = (t < nb) ? bsum[t] : 0;
    sh[t] = v; __syncthreads();
    for (int off = 1; off < 256; off <<= 1) {
        int x = (t >= off) ? sh[t - off] : 0;
        __syncthreads();
        sh[t] += x;
        __syncthreads();
    }
    if (t < nb) bsum[t] = sh[t] - v;
}

__global__ void scan3(int* __restrict__ offs, const int* __restrict__ bsum, int n)
{
    int i = blockIdx.x * 256 + threadIdx.x;
    if (i == 0) offs[0] = 0;
    if (i < n) offs[i + 1] += bsum[i >> 11];
}

// scatter: ecv[pos] = (col, val_fp32) — dtype conversion applied once here
__global__ void scatter(const int* __restrict__ rows, const int* __restrict__ cols,
    const void* __restrict__ vals, const int* __restrict__ flag,
    const int* __restrict__ offs, int* __restrict__ fill, int2* __restrict__ ecv,
    int n, int nnz)
{
    int e = blockIdx.x * 256 + threadIdx.x;
    if (e >= nnz) return;
    int r = rows[e], c = cols[e];
    if ((unsigned)r >= (unsigned)n || (unsigned)c >= (unsigned)n) return;
    int pos = offs[r] + atomicAdd(&fill[r], 1);
    float v = ldf(vals, e, *flag);
    ecv[pos] = make_int2(c, __float_as_int(v));
}

// ---------- CSR SpMM: one wave per row, no atomics, full D in one pass ----------
// Lane l (0..49 active) owns columns d=2l, 2l+1 (one 4B = 2xbf16 load per edge).

__global__ void spmm_csr(const int* __restrict__ offs, const int2* __restrict__ ecv,
    const bf16* __restrict__ X, bf16* __restrict__ Y, int n)
{
    int wid = (int)(((long long)blockIdx.x * 256 + threadIdx.x) >> 6);
    int lane = threadIdx.x & 63;
    if (wid >= n) return;
    int s = offs[wid], e = offs[wid + 1];
    int d0 = lane * 2;
    if (d0 >= D) return;
    float a0 = 0.f, a1 = 0.f;
    int j = s;
    for (; j + 1 < e; j += 2) {     // unroll-2: two gathers in flight
        int2 cv0 = ecv[j];
        int2 cv1 = ecv[j + 1];
        unsigned int u0 = *(const unsigned int*)(X + (long long)cv0.x * D + d0);
        unsigned int u1 = *(const unsigned int*)(X + (long long)cv1.x * D + d0);
        float v0 = __int_as_float(cv0.y);
        float v1 = __int_as_float(cv1.y);
        a0 = fmaf(v0, b2f((unsigned short)u0), a0);
        a1 = fmaf(v0, b2f((unsigned short)(u0 >> 16)), a1);
        a0 = fmaf(v1, b2f((unsigned short)u1), a0);
        a1 = fmaf(v1, b2f((unsigned short)(u1 >> 16)), a1);
    }
    if (j < e) {
        int2 cv = ecv[j];
        unsigned int u = *(const unsigned int*)(X + (long long)cv.x * D + d0);
        float v = __int_as_float(cv.y);
        a0 = fmaf(v, b2f((unsigned short)u), a0);
        a1 = fmaf(v, b2f((unsigned short)(u >> 16)), a1);
    }
    *(unsigned int*)(Y + (long long)wid * D + d0) =
        ((unsigned int)f2bu(a1) << 16) | f2bu(a0);
}

// ---------- in-place row softmax on bf16 [n, D] ----------

__global__ void softmax_rows(bf16* __restrict__ L, int n)
{
    __shared__ float red[128];
    __shared__ float m_s, s_s;
    int r = blockIdx.x;
    if (r >= n) return;
    int d = threadIdx.x;
    float x = (d < D) ? __bfloat162float(L[(long long)r * D + d]) : -3.0e38f;
    red[d] = x; __syncthreads();
    for (int off = 64; off; off >>= 1) {
        if (d < off) red[d] = fmaxf(red[d], red[d + off]);
        __syncthreads();
    }
    if (d == 0) m_s = red[0];
    __syncthreads();
    float e = (d < D) ? __expf(x - m_s) : 0.0f;
    red[d] = e; __syncthreads();
    for (int off = 64; off; off >>= 1) {
        if (d < off) red[d] += red[d + off];
        __syncthreads();
    }
    if (d == 0) s_s = red[0];
    __syncthreads();
    if (d < D) L[(long long)r * D + d] = __float2bfloat16(e / s_s);
}

// ---------- hsm[k,d] = sum_n H1[n,k] * X2[n,d] ----------
// Split-K outer-product GEMM (register-tiled), one atomicAdd per elem per block.

#define HSM_G 500
#define HSM_BATCH 10

__global__ void hsm_outer(const bf16* __restrict__ H1, const bf16* __restrict__ X2,
    float* __restrict__ hsm, int n)
{
    __shared__ float sh[HSM_BATCH][D];   // H1 rows (k)
    __shared__ float sx[HSM_BATCH][D];   // X2 rows (d)
    const int t = threadIdx.x;
    const int tk = t / 10;               // 0..24 active (t < 250)
    const int td = t - tk * 10;          // 0..9

    float acc[4][10];
    #pragma unroll
    for (int i = 0; i < 4; ++i)
        #pragma unroll
        for (int j = 0; j < 10; ++j) acc[i][j] = 0.f;

    const int per = (n + HSM_G - 1) / HSM_G;     // 200 for n = 100000
    const int s = blockIdx.x * per;
    int e = s + per; if (e > n) e = n;

    for (int base = s; base < e; base += HSM_BATCH) {
        int cnt = e - base; if (cnt > HSM_BATCH) cnt = HSM_BATCH;
        __syncthreads();   // protect LDS of previous batch before overwrite
        for (int v = t; v < cnt * 25; v += 256) {
            int r = v / 25, c4 = v - (v / 25) * 25;
            ushort4 h4 = *(const ushort4*)(H1 + (long long)(base + r) * D + 4 * c4);
            ushort4 x4 = *(const ushort4*)(X2 + (long long)(base + r) * D + 4 * c4);
            sh[r][4 * c4 + 0] = b2f(h4.x);
            sh[r][4 * c4 + 1] = b2f(h4.y);
            sh[r][4 * c4 + 2] = b2f(h4.z);
            sh[r][4 * c4 + 3] = b2f(h4.w);
            sx[r][4 * c4 + 0] = b2f(x4.x);
            sx[r][4 * c4 + 1] = b2f(x4.y);
            sx[r][4 * c4 + 2] = b2f(x4.z);
            sx[r][4 * c4 + 3] = b2f(x4.w);
        }
        __syncthreads();
        if (t < 250) {
            #pragma unroll
            for (int r = 0; r < HSM_BATCH; ++r) {
                if (r < cnt) {
                    float4 a = *(const float4*)&sh[r][tk * 4];
                    float b[10];
                    #pragma unroll
                    for (int j = 0; j < 10; ++j) b[j] = sx[r][td * 10 + j];
                    #pragma unroll
                    for (int j = 0; j < 10; ++j) {
                        acc[0][j] = fmaf(a.x, b[j], acc[0][j]);
                        acc[1][j] = fmaf(a.y, b[j], acc[1][j]);
                        acc[2][j] = fmaf(a.z, b[j], acc[2][j]);
                        acc[3][j] = fmaf(a.w, b[j], acc[3][j]);
                    }
                }
            }
        }
    }

    if (t < 250) {
        #pragma unroll
        for (int i = 0; i < 4; ++i)
            #pragma unroll
            for (int j = 0; j < 10; ++j)
                atomicAdd(&hsm[(tk * 4 + i) * D + td * 10 + j], acc[i][j]);
    }
}

// ---- finrow: x_new = hN + x2 (into X); o0 += l2n(x_new); o1 += l2n(hN) (fp32) ----

__global__ void finrow(const bf16* __restrict__ Hn, bf16* __restrict__ X,
    float* __restrict__ o0, float* __restrict__ o1, int n)
{
    __shared__ float red[128];
    __shared__ float ia_s, ib_s;
    int r = blockIdx.x;
    if (r >= n) return;
    int d = threadIdx.x;
    long long b = (long long)r * D;
    float hn = (d < D) ? __bfloat162float(Hn[b + d]) : 0.f;
    float x2 = (d < D) ? __bfloat162float(X[b + d]) : 0.f;
    float xn = hn + x2;
    red[d] = xn * xn; __syncthreads();
    for (int off = 64; off; off >>= 1) {
        if (d < off) red[d] += red[d + off];
        __syncthreads();
    }
    if (d == 0) ia_s = 1.0f / fmaxf(sqrtf(red[0]), 1e-12f);
    __syncthreads();
    red[d] = hn * hn; __syncthreads();
    for (int off = 64; off; off >>= 1) {
        if (d < off) red[d] += red[d + off];
        __syncthreads();
    }
    if (d == 0) ib_s = 1.0f / fmaxf(sqrtf(red[0]), 1e-12f);
    __syncthreads();
    if (d < D) {
        X[b + d] = __float2bfloat16(xn);
        o0[b + d] += xn * ia_s;
        o1[b + d] += hn * ib_s;
    }
}

// ---------- host ----------

extern "C" void kernel_launch(void* const* d_in, const int* in_sizes, int n_in,
                              void* d_out, int out_size, void* d_ws, size_t ws_size,
                              hipStream_t stream)
{
    const void* emb   = d_in[0];
    // d_in[1] = adj: cancels exactly in column-normalization (softmax rows sum to 1)
    const void* evals = d_in[2];
    const void* Wit   = d_in[3];
    const void* Wi1   = d_in[4];
    const void* Wi2   = d_in[5];
    const int* erows  = (const int*)d_in[6];
    const int* ecols  = (const int*)d_in[7];
    const int N   = in_sizes[0] / D;
    const int NNZ = in_sizes[2];
    const long long ND = (long long)N * D;

    float* o0 = (float*)d_out;      // item_embeddings accumulator (fp32 output!)
    float* o1 = o0 + ND;            // hs accumulator

    char* base = (char*)d_ws;
    size_t off = 0;
    auto alloc = [&](size_t bytes) -> void* {
        void* r = base + off;
        off += (bytes + 255) & ~(size_t)255;
        return r;
    };
    int*   flag = (int*)  alloc(256);
    float* hsm  = (float*)alloc(D * D * 4);
    float* Wf   = (float*)alloc(5 * D * D * 4);
    int*   offs = (int*)  alloc(((size_t)N + 1) * 4);
    int*   cnt  = (int*)  alloc((size_t)N * 4);        // also reused as scatter fill
    int*   bsum = (int*)  alloc(1024);
    int2*  ecv  = (int2*) alloc((size_t)NNZ * 8);
    bf16*  B1   = (bf16*) alloc(ND * 2);
    bf16*  B2   = (bf16*) alloc(ND * 2);
    bf16*  H1   = (bf16*) alloc(ND * 2);

    const int gND = (int)((ND + 255) / 256);
    const int gE  = (NNZ + 255) / 256;
    const int nb  = (N + 2047) / 2048;          // scan blocks (<= 256)

    detectk<<<1, 256, 0, stream>>>(emb, flag);
    convw<<<(50000 + 255) / 256, 256, 0, stream>>>(Wit, Wi1, Wi2, flag, Wf);
    initk<<<gND, 256, 0, stream>>>(emb, flag, B1, o0, o1, (int)ND);

    // ---- one-time CSR build ----
    hipMemsetAsync(cnt, 0, (size_t)N * 4, stream);
    hist<<<gE, 256, 0, stream>>>(erows, ecols, cnt, N, NNZ);
    scan1<<<nb, 256, 0, stream>>>(cnt, offs, bsum, N);
    scan2<<<1, 256, 0, stream>>>(bsum, nb);
    scan3<<<(N + 255) / 256, 256, 0, stream>>>(offs, bsum, N);
    hipMemsetAsync(cnt, 0, (size_t)N * 4, stream);   // reuse as fill counters
    scatter<<<gE, 256, 0, stream>>>(erows, ecols, evals, flag, offs, cnt, ecv, N, NNZ);

    const int gS = (N + 3) / 4;   // spmm: 4 waves (rows) per 256-thread block

    for (int l = 0; l < 3; ++l) {
        mm_naive<<<gND, 256, 0, stream>>>(B1, Wf + l * 10000, B2, N);   // B2 = x@W
        spmm_csr<<<gS, 256, 0, stream>>>(offs, ecv, B2, B1, N);         // B1 = A@B2
        mm_addrelu<<<gND, 256, 0, stream>>>(B1, Wf + 30000, B2, N);     // B2 = relu(x2@W1+x2)
        mm_naive<<<gND, 256, 0, stream>>>(B2, Wf + 40000, H1, N);       // H1 = logits
        softmax_rows<<<N, 128, 0, stream>>>(H1, N);                     // H1 = softmax
        hipMemsetAsync(hsm, 0, D * D * 4, stream);
        hsm_outer<<<HSM_G, 256, 0, stream>>>(H1, B1, hsm, N);           // hsm = H1^T@x2
        mm_naive<<<gND, 256, 0, stream>>>(H1, hsm, B2, N);              // B2 = hN
        finrow<<<N, 128, 0, stream>>>(B2, B1, o0, o1, N);               // B1 = x_new; accum
    }
    fink<<<gND, 256, 0, stream>>>(o0, o1, (int)ND);
}

// Round 3
// 3708.442 us; speedup vs baseline: 2.1715x; 1.2183x over previous
//
#include <hip/hip_runtime.h>
#include <hip/hip_bf16.h>

#define D 100

typedef __hip_bfloat16 bf16;

__device__ __forceinline__ float ldf(const void* p, long long i, int f32) {
    return f32 ? ((const float*)p)[i] : __bfloat162float(((const bf16*)p)[i]);
}

__device__ __forceinline__ float b2f(unsigned short u) {
    return __uint_as_float(((unsigned int)u) << 16);
}

__device__ __forceinline__ unsigned short f2bu(float x) {
    union { bf16 b; unsigned short u; } cv;
    cv.b = __float2bfloat16(x);
    return cv.u;
}

// ---------- input dtype detector: 0 = bf16, 1 = fp32 ----------
__global__ void detectk(const void* __restrict__ emb, int* __restrict__ flag)
{
    const unsigned short* u = (const unsigned short*)emb;
    __shared__ int cnt;
    if (threadIdx.x == 0) cnt = 0;
    __syncthreads();
    int good = 0;
    for (int i = threadIdx.x; i < 512; i += 256) {
        int e = (u[i] >> 7) & 0xFF;
        if (e >= 118 && e <= 137) good++;
    }
    atomicAdd(&cnt, good);
    __syncthreads();
    if (threadIdx.x == 0) *flag = (cnt >= 410) ? 0 : 1;
}

// ---------- input conversions ----------

__global__ void convw(const void* __restrict__ wi, const void* __restrict__ w1,
    const void* __restrict__ w2, const int* __restrict__ flag, float* __restrict__ Wf)
{
    int i = blockIdx.x * 256 + threadIdx.x;
    int f = *flag;
    if (i < 30000)      Wf[i] = ldf(wi, i, f);
    else if (i < 40000) Wf[i] = ldf(w1, i - 30000, f);
    else if (i < 50000) Wf[i] = ldf(w2, i - 40000, f);
}

// o0, o1 are FLOAT32 (output dtype follows the reference: jnp.float32).
__global__ void initk(const void* __restrict__ emb, const int* __restrict__ flag,
    bf16* __restrict__ x, float* __restrict__ o0, float* __restrict__ o1, int n)
{
    int i = blockIdx.x * 256 + threadIdx.x;
    if (i < n) {
        float v = ldf(emb, i, *flag);
        x[i] = __float2bfloat16(v);
        o0[i] = v;          // final[0] = raw embedding (scaled by 1/4 in fink)
        o1[i] = 0.0f;
    }
}

__global__ void fink(float* __restrict__ o0, float* __restrict__ o1, int nd)
{
    int i = blockIdx.x * 256 + threadIdx.x;
    if (i < nd) {
        o0[i] *= 0.25f;             // /(L+1)
        o1[i] *= (1.0f / 3.0f);     // /L
    }
}

// ---------- naive GEMM: Y[n,c] = sum_d X[n,d] * W[d,c] ----------

__global__ void mm_naive(const bf16* __restrict__ X, const float* __restrict__ W,
    bf16* __restrict__ Y, int n)
{
    long long t = (long long)blockIdx.x * 256 + threadIdx.x;
    if (t >= (long long)n * D) return;
    int nn = (int)(t / D), c = (int)(t - (long long)nn * D);
    const bf16* xr = X + (long long)nn * D;
    float acc = 0.f;
    for (int d = 0; d < D; ++d)
        acc = fmaf(__bfloat162float(xr[d]), W[d * D + c], acc);
    Y[t] = __float2bfloat16(acc);
}

// ---------- naive: Y = relu(X @ W + X) ----------

__global__ void mm_addrelu(const bf16* __restrict__ X, const float* __restrict__ W,
    bf16* __restrict__ Y, int n)
{
    long long t = (long long)blockIdx.x * 256 + threadIdx.x;
    if (t >= (long long)n * D) return;
    int nn = (int)(t / D), c = (int)(t - (long long)nn * D);
    const bf16* xr = X + (long long)nn * D;
    float acc = 0.f;
    for (int d = 0; d < D; ++d)
        acc = fmaf(__bfloat162float(xr[d]), W[d * D + c], acc);
    acc += __bfloat162float(xr[c]);
    Y[t] = __float2bfloat16(fmaxf(acc, 0.0f));
}

// ---------- CSR construction (one-time; edge structure constant across layers) ----------

__global__ void hist(const int* __restrict__ rows, const int* __restrict__ cols,
    int* __restrict__ cnt, int n, int nnz)
{
    int e = blockIdx.x * 256 + threadIdx.x;
    if (e >= nnz) return;
    int r = rows[e], c = cols[e];
    if ((unsigned)r >= (unsigned)n || (unsigned)c >= (unsigned)n) return;
    atomicAdd(&cnt[r], 1);
}

// scan1: per-block (2048 elems) inclusive scan of cnt into offs[i+1]; block sums to bsum
__global__ void scan1(const int* __restrict__ cnt, int* __restrict__ offs,
    int* __restrict__ bsum, int n)
{
    __shared__ int sh[256];
    int b = blockIdx.x, t = threadIdx.x;
    int base = b * 2048 + t * 8;
    int v[8];
    int s = 0;
    #pragma unroll
    for (int i = 0; i < 8; ++i) {
        int idx = base + i;
        v[i] = (idx < n) ? cnt[idx] : 0;
        s += v[i];
    }
    sh[t] = s; __syncthreads();
    for (int off = 1; off < 256; off <<= 1) {
        int x = (t >= off) ? sh[t - off] : 0;
        __syncthreads();
        sh[t] += x;
        __syncthreads();
    }
    int run = sh[t] - s;   // exclusive prefix of this thread's chunk
    #pragma unroll
    for (int i = 0; i < 8; ++i) {
        run += v[i];
        int idx = base + i;
        if (idx < n) offs[idx + 1] = run;
    }
    if (t == 255) bsum[b] = sh[255];
}

// scan2: single block, exclusive scan of block sums (nb <= 256)
__global__ void scan2(int* __restrict__ bsum, int nb)
{
    __shared__ int sh[256];
    int t = threadIdx.x;
    int v = (t < nb) ? bsum[t] : 0;
    sh[t] = v; __syncthreads();
    for (int off = 1; off < 256; off <<= 1) {
        int x = (t >= off) ? sh[t - off] : 0;
        __syncthreads();
        sh[t] += x;
        __syncthreads();
    }
    if (t < nb) bsum[t] = sh[t] - v;
}

__global__ void scan3(int* __restrict__ offs, const int* __restrict__ bsum, int n)
{
    int i = blockIdx.x * 256 + threadIdx.x;
    if (i == 0) offs[0] = 0;
    if (i < n) offs[i + 1] += bsum[i >> 11];
}

// scatter: ecv[pos] = (col, val_fp32) — dtype conversion applied once here
__global__ void scatter(const int* __restrict__ rows, const int* __restrict__ cols,
    const void* __restrict__ vals, const int* __restrict__ flag,
    const int* __restrict__ offs, int* __restrict__ fill, int2* __restrict__ ecv,
    int n, int nnz)
{
    int e = blockIdx.x * 256 + threadIdx.x;
    if (e >= nnz) return;
    int r = rows[e], c = cols[e];
    if ((unsigned)r >= (unsigned)n || (unsigned)c >= (unsigned)n) return;
    int pos = offs[r] + atomicAdd(&fill[r], 1);
    float v = ldf(vals, e, *flag);
    ecv[pos] = make_int2(c, __float_as_int(v));
}

// ---------- CSR SpMM: one wave per row, no atomics, full D in one pass ----------
// Lane l (0..49 active) owns columns d=2l, 2l+1 (one 4B = 2xbf16 load per edge).

__global__ void spmm_csr(const int* __restrict__ offs, const int2* __restrict__ ecv,
    const bf16* __restrict__ X, bf16* __restrict__ Y, int n)
{
    int wid = (int)(((long long)blockIdx.x * 256 + threadIdx.x) >> 6);
    int lane = threadIdx.x & 63;
    if (wid >= n) return;
    int s = offs[wid], e = offs[wid + 1];
    int d0 = lane * 2;
    if (d0 >= D) return;
    float a0 = 0.f, a1 = 0.f;
    int j = s;
    for (; j + 1 < e; j += 2) {     // unroll-2: two gathers in flight
        int2 cv0 = ecv[j];
        int2 cv1 = ecv[j + 1];
        unsigned int u0 = *(const unsigned int*)(X + (long long)cv0.x * D + d0);
        unsigned int u1 = *(const unsigned int*)(X + (long long)cv1.x * D + d0);
        float v0 = __int_as_float(cv0.y);
        float v1 = __int_as_float(cv1.y);
        a0 = fmaf(v0, b2f((unsigned short)u0), a0);
        a1 = fmaf(v0, b2f((unsigned short)(u0 >> 16)), a1);
        a0 = fmaf(v1, b2f((unsigned short)u1), a0);
        a1 = fmaf(v1, b2f((unsigned short)(u1 >> 16)), a1);
    }
    if (j < e) {
        int2 cv = ecv[j];
        unsigned int u = *(const unsigned int*)(X + (long long)cv.x * D + d0);
        float v = __int_as_float(cv.y);
        a0 = fmaf(v, b2f((unsigned short)u), a0);
        a1 = fmaf(v, b2f((unsigned short)(u >> 16)), a1);
    }
    *(unsigned int*)(Y + (long long)wid * D + d0) =
        ((unsigned int)f2bu(a1) << 16) | f2bu(a0);
}

// ---------- in-place row softmax on bf16 [n, D] ----------

__global__ void softmax_rows(bf16* __restrict__ L, int n)
{
    __shared__ float red[128];
    __shared__ float m_s, s_s;
    int r = blockIdx.x;
    if (r >= n) return;
    int d = threadIdx.x;
    float x = (d < D) ? __bfloat162float(L[(long long)r * D + d]) : -3.0e38f;
    red[d] = x; __syncthreads();
    for (int off = 64; off; off >>= 1) {
        if (d < off) red[d] = fmaxf(red[d], red[d + off]);
        __syncthreads();
    }
    if (d == 0) m_s = red[0];
    __syncthreads();
    float e = (d < D) ? __expf(x - m_s) : 0.0f;
    red[d] = e; __syncthreads();
    for (int off = 64; off; off >>= 1) {
        if (d < off) red[d] += red[d + off];
        __syncthreads();
    }
    if (d == 0) s_s = red[0];
    __syncthreads();
    if (d < D) L[(long long)r * D + d] = __float2bfloat16(e / s_s);
}

// ---------- hsm[k,d] = sum_n H1[n,k] * X2[n,d] ----------
// Stage 1: split-K outer-product GEMM, register-tiled 4(k) x 10(d) per thread.
// Each block PLAIN-STORES its 100x100 fp32 partial tile (no atomics — the
// round-2 counters showed 5M device-scope atomicAdds = 156 MB write-through
// and ~700 ns serialized RMW per same-address chain).
// Stage 2: hsm_reduce sums the 500 partial tiles (coalesced, no memset needed).

#define HSM_G 500
#define HSM_BATCH 32

__global__ void hsm_partial(const bf16* __restrict__ H1, const bf16* __restrict__ X2,
    float* __restrict__ partials, int n)
{
    __shared__ float sh[HSM_BATCH][D];   // H1 rows (k)
    __shared__ float sx[HSM_BATCH][D];   // X2 rows (d)
    const int t = threadIdx.x;
    const int tk = t / 10;               // 0..24 active (t < 250)
    const int td = t - tk * 10;          // 0..9

    float acc[4][10];
    #pragma unroll
    for (int i = 0; i < 4; ++i)
        #pragma unroll
        for (int j = 0; j < 10; ++j) acc[i][j] = 0.f;

    const int per = (n + HSM_G - 1) / HSM_G;     // 200 for n = 100000
    const int s = blockIdx.x * per;
    int e = s + per; if (e > n) e = n;

    for (int base = s; base < e; base += HSM_BATCH) {
        int cnt = e - base; if (cnt > HSM_BATCH) cnt = HSM_BATCH;
        __syncthreads();   // protect LDS of previous batch before overwrite
        for (int v = t; v < cnt * 25; v += 256) {
            int r = v / 25, c4 = v - (v / 25) * 25;
            ushort4 h4 = *(const ushort4*)(H1 + (long long)(base + r) * D + 4 * c4);
            ushort4 x4 = *(const ushort4*)(X2 + (long long)(base + r) * D + 4 * c4);
            sh[r][4 * c4 + 0] = b2f(h4.x);
            sh[r][4 * c4 + 1] = b2f(h4.y);
            sh[r][4 * c4 + 2] = b2f(h4.z);
            sh[r][4 * c4 + 3] = b2f(h4.w);
            sx[r][4 * c4 + 0] = b2f(x4.x);
            sx[r][4 * c4 + 1] = b2f(x4.y);
            sx[r][4 * c4 + 2] = b2f(x4.z);
            sx[r][4 * c4 + 3] = b2f(x4.w);
        }
        __syncthreads();
        if (t < 250) {
            #pragma unroll 8
            for (int r = 0; r < cnt; ++r) {
                float4 a = *(const float4*)&sh[r][tk * 4];
                float b[10];
                #pragma unroll
                for (int j = 0; j < 10; ++j) b[j] = sx[r][td * 10 + j];
                #pragma unroll
                for (int j = 0; j < 10; ++j) {
                    acc[0][j] = fmaf(a.x, b[j], acc[0][j]);
                    acc[1][j] = fmaf(a.y, b[j], acc[1][j]);
                    acc[2][j] = fmaf(a.z, b[j], acc[2][j]);
                    acc[3][j] = fmaf(a.w, b[j], acc[3][j]);
                }
            }
        }
    }

    if (t < 250) {
        float* out = partials + (long long)blockIdx.x * (D * D);
        #pragma unroll
        for (int i = 0; i < 4; ++i)
            #pragma unroll
            for (int j = 0; j < 10; ++j)
                out[(tk * 4 + i) * D + td * 10 + j] = acc[i][j];
    }
}

__global__ void hsm_reduce(const float* __restrict__ partials, float* __restrict__ hsm)
{
    int i = blockIdx.x * 256 + threadIdx.x;
    if (i >= D * D) return;
    float s0 = 0.f, s1 = 0.f, s2 = 0.f, s3 = 0.f;
    #pragma unroll 4
    for (int b = 0; b < HSM_G; b += 4) {
        s0 += partials[(long long)(b + 0) * (D * D) + i];
        s1 += partials[(long long)(b + 1) * (D * D) + i];
        s2 += partials[(long long)(b + 2) * (D * D) + i];
        s3 += partials[(long long)(b + 3) * (D * D) + i];
    }
    hsm[i] = (s0 + s1) + (s2 + s3);
}

// ---- finrow: x_new = hN + x2 (into X); o0 += l2n(x_new); o1 += l2n(hN) (fp32) ----

__global__ void finrow(const bf16* __restrict__ Hn, bf16* __restrict__ X,
    float* __restrict__ o0, float* __restrict__ o1, int n)
{
    __shared__ float red[128];
    __shared__ float ia_s, ib_s;
    int r = blockIdx.x;
    if (r >= n) return;
    int d = threadIdx.x;
    long long b = (long long)r * D;
    float hn = (d < D) ? __bfloat162float(Hn[b + d]) : 0.f;
    float x2 = (d < D) ? __bfloat162float(X[b + d]) : 0.f;
    float xn = hn + x2;
    red[d] = xn * xn; __syncthreads();
    for (int off = 64; off; off >>= 1) {
        if (d < off) red[d] += red[d + off];
        __syncthreads();
    }
    if (d == 0) ia_s = 1.0f / fmaxf(sqrtf(red[0]), 1e-12f);
    __syncthreads();
    red[d] = hn * hn; __syncthreads();
    for (int off = 64; off; off >>= 1) {
        if (d < off) red[d] += red[d + off];
        __syncthreads();
    }
    if (d == 0) ib_s = 1.0f / fmaxf(sqrtf(red[0]), 1e-12f);
    __syncthreads();
    if (d < D) {
        X[b + d] = __float2bfloat16(xn);
        o0[b + d] += xn * ia_s;
        o1[b + d] += hn * ib_s;
    }
}

// ---------- host ----------

extern "C" void kernel_launch(void* const* d_in, const int* in_sizes, int n_in,
                              void* d_out, int out_size, void* d_ws, size_t ws_size,
                              hipStream_t stream)
{
    const void* emb   = d_in[0];
    // d_in[1] = adj: cancels exactly in column-normalization (softmax rows sum to 1)
    const void* evals = d_in[2];
    const void* Wit   = d_in[3];
    const void* Wi1   = d_in[4];
    const void* Wi2   = d_in[5];
    const int* erows  = (const int*)d_in[6];
    const int* ecols  = (const int*)d_in[7];
    const int N   = in_sizes[0] / D;
    const int NNZ = in_sizes[2];
    const long long ND = (long long)N * D;

    float* o0 = (float*)d_out;      // item_embeddings accumulator (fp32 output!)
    float* o1 = o0 + ND;            // hs accumulator

    char* base = (char*)d_ws;
    size_t off = 0;
    auto alloc = [&](size_t bytes) -> void* {
        void* r = base + off;
        off += (bytes + 255) & ~(size_t)255;
        return r;
    };
    int*   flag = (int*)  alloc(256);
    float* hsm  = (float*)alloc(D * D * 4);
    float* Wf   = (float*)alloc(5 * D * D * 4);
    int*   offs = (int*)  alloc(((size_t)N + 1) * 4);
    int*   cnt  = (int*)  alloc((size_t)N * 4);        // also reused as scatter fill
    int*   bsum = (int*)  alloc(1024);
    int2*  ecv  = (int2*) alloc((size_t)NNZ * 8);
    bf16*  B1   = (bf16*) alloc(ND * 2);
    bf16*  B2   = (bf16*) alloc(ND * 2);
    bf16*  H1   = (bf16*) alloc(ND * 2);
    // partials (HSM_G * 10000 * 4 B = 20.0 MB) aliases B2: B2 is dead between
    // softmax_rows (consumed its producer) and the mm_naive that writes hN.
    float* partials = (float*)B2;

    const int gND = (int)((ND + 255) / 256);
    const int gE  = (NNZ + 255) / 256;
    const int nb  = (N + 2047) / 2048;          // scan blocks (<= 256)

    detectk<<<1, 256, 0, stream>>>(emb, flag);
    convw<<<(50000 + 255) / 256, 256, 0, stream>>>(Wit, Wi1, Wi2, flag, Wf);
    initk<<<gND, 256, 0, stream>>>(emb, flag, B1, o0, o1, (int)ND);

    // ---- one-time CSR build ----
    hipMemsetAsync(cnt, 0, (size_t)N * 4, stream);
    hist<<<gE, 256, 0, stream>>>(erows, ecols, cnt, N, NNZ);
    scan1<<<nb, 256, 0, stream>>>(cnt, offs, bsum, N);
    scan2<<<1, 256, 0, stream>>>(bsum, nb);
    scan3<<<(N + 255) / 256, 256, 0, stream>>>(offs, bsum, N);
    hipMemsetAsync(cnt, 0, (size_t)N * 4, stream);   // reuse as fill counters
    scatter<<<gE, 256, 0, stream>>>(erows, ecols, evals, flag, offs, cnt, ecv, N, NNZ);

    const int gS = (N + 3) / 4;   // spmm: 4 waves (rows) per 256-thread block

    for (int l = 0; l < 3; ++l) {
        mm_naive<<<gND, 256, 0, stream>>>(B1, Wf + l * 10000, B2, N);   // B2 = x@W
        spmm_csr<<<gS, 256, 0, stream>>>(offs, ecv, B2, B1, N);         // B1 = A@B2
        mm_addrelu<<<gND, 256, 0, stream>>>(B1, Wf + 30000, B2, N);     // B2 = relu(x2@W1+x2)
        mm_naive<<<gND, 256, 0, stream>>>(B2, Wf + 40000, H1, N);       // H1 = logits
        softmax_rows<<<N, 128, 0, stream>>>(H1, N);                     // H1 = softmax
        hsm_partial<<<HSM_G, 256, 0, stream>>>(H1, B1, partials, N);    // partials (alias B2)
        hsm_reduce<<<(D * D + 255) / 256, 256, 0, stream>>>(partials, hsm);
        mm_naive<<<gND, 256, 0, stream>>>(H1, hsm, B2, N);              // B2 = hN
        finrow<<<N, 128, 0, stream>>>(B2, B1, o0, o1, N);               // B1 = x_new; accum
    }
    fink<<<gND, 256, 0, stream>>>(o0, o1, (int)ND);
}

// Round 4
// 1710.002 us; speedup vs baseline: 4.7094x; 2.1687x over previous
//
#include <hip/hip_runtime.h>
#include <hip/hip_bf16.h>

#define D 100
#define XS 128   // padded row stride (elements) for all activation buffers

typedef __hip_bfloat16 bf16;
typedef __attribute__((ext_vector_type(8))) short bf16x8;
typedef __attribute__((ext_vector_type(4))) float f32x4;

__device__ __forceinline__ float ldf(const void* p, long long i, int f32) {
    return f32 ? ((const float*)p)[i] : __bfloat162float(((const bf16*)p)[i]);
}

__device__ __forceinline__ float b2f(unsigned short u) {
    return __uint_as_float(((unsigned int)u) << 16);
}

__device__ __forceinline__ unsigned short f2bu(float x) {
    union { bf16 b; unsigned short u; } cv;
    cv.b = __float2bfloat16(x);
    return cv.u;
}

// ---------- input dtype detector: 0 = bf16, 1 = fp32 ----------
__global__ void detectk(const void* __restrict__ emb, int* __restrict__ flag)
{
    const unsigned short* u = (const unsigned short*)emb;
    __shared__ int cnt;
    if (threadIdx.x == 0) cnt = 0;
    __syncthreads();
    int good = 0;
    for (int i = threadIdx.x; i < 512; i += 256) {
        int e = (u[i] >> 7) & 0xFF;
        if (e >= 118 && e <= 137) good++;
    }
    atomicAdd(&cnt, good);
    __syncthreads();
    if (threadIdx.x == 0) *flag = (cnt >= 410) ? 0 : 1;
}

// ---------- weight prep: 5 matrices -> transposed, padded [112][128], hi/lo bf16 ----
// Wt[c][k] = W[k][c]; hi = bf16(w), lo = bf16(w - hi). Pad region = 0 exactly.

__global__ void wprep(const void* __restrict__ wi, const void* __restrict__ w1,
    const void* __restrict__ w2, const int* __restrict__ flag,
    bf16* __restrict__ wh, bf16* __restrict__ wl)
{
    int i = blockIdx.x * 256 + threadIdx.x;
    if (i >= 5 * 112 * 128) return;
    int m = i / (112 * 128), rem = i - m * (112 * 128);
    int c = rem / 128, k = rem - c * 128;
    float w = 0.f;
    if (c < D && k < D) {
        int f = *flag;
        long long si = (long long)k * D + c;
        if (m < 3)       w = ldf(wi, m * 10000 + si, f);
        else if (m == 3) w = ldf(w1, si, f);
        else             w = ldf(w2, si, f);
    }
    bf16 hb = __float2bfloat16(w);
    wh[i] = hb;
    wl[i] = __float2bfloat16(w - __bfloat162float(hb));
}

// ---------- per-layer hsm (fp32 [100][100]) -> transposed padded hi/lo ----------

__global__ void hsm_conv(const float* __restrict__ hsm, bf16* __restrict__ hh,
    bf16* __restrict__ hl)
{
    int i = blockIdx.x * 256 + threadIdx.x;
    if (i >= 112 * 128) return;
    int c = i / 128, k = i - c * 128;
    float w = (c < D && k < D) ? hsm[k * D + c] : 0.f;
    bf16 hb = __float2bfloat16(w);
    hh[i] = hb;
    hl[i] = __float2bfloat16(w - __bfloat162float(hb));
}

// o0, o1 are FLOAT32 (output dtype follows the reference: jnp.float32).
__global__ void initk(const void* __restrict__ emb, const int* __restrict__ flag,
    bf16* __restrict__ x, float* __restrict__ o0, float* __restrict__ o1, int nd)
{
    int i = blockIdx.x * 256 + threadIdx.x;
    if (i < nd) {
        int n = i / D, d = i - n * D;
        float v = ldf(emb, i, *flag);
        x[(long long)n * XS + d] = __float2bfloat16(v);
        o0[i] = v;          // final[0] = raw embedding (scaled by 1/4 in fink)
        o1[i] = 0.0f;
    }
}

__global__ void fink(float* __restrict__ o0, float* __restrict__ o1, int nd)
{
    int i = blockIdx.x * 256 + threadIdx.x;
    if (i < nd) {
        o0[i] *= 0.25f;             // /(L+1)
        o1[i] *= (1.0f / 3.0f);     // /L
    }
}

// ---------- MFMA GEMM: Y[n, 0..100) = X[n,:] @ W ----------
// W given as transposed padded hi/lo bf16 [112][128] (wprep/hsm_conv layout).
// mode 0: Y = X@W.  mode 1: Y = relu(X@W + X).
// 4 waves/block; wave owns 32 rows x 112 cols: acc[2 row-tiles][7 n-tiles].
// A-frag: row = lane&15, k = (lane>>4)*8 + j (8 consecutive bf16 = 16 B).
// C/D:    col = lane&15, row = (lane>>4)*4 + reg  [measured m89/m91].
// Activation pads (cols 100..127) are exact zeros -> k-padding contributes 0.
// Rows >= n may read garbage A (next buffer); row-local in D, stores guarded.

__global__ __launch_bounds__(256) void gemm_mfma(
    const bf16* __restrict__ X, const bf16* __restrict__ Wh,
    const bf16* __restrict__ Wl, bf16* __restrict__ Y, int n, int mode)
{
    const int wave = threadIdx.x >> 6;
    const int lane = threadIdx.x & 63;
    const int r16 = lane & 15, kg = lane >> 4;
    const long long m0 = ((long long)blockIdx.x * 4 + wave) * 32;

    f32x4 acc[2][7];
    #pragma unroll
    for (int i = 0; i < 2; ++i)
        #pragma unroll
        for (int j = 0; j < 7; ++j) acc[i][j] = (f32x4){0.f, 0.f, 0.f, 0.f};

    const bf16* xa = X + (m0 + r16) * XS + kg * 8;
    #pragma unroll
    for (int ks = 0; ks < 4; ++ks) {
        bf16x8 a0 = *(const bf16x8*)(xa + ks * 32);
        bf16x8 a1 = *(const bf16x8*)(xa + 16 * XS + ks * 32);
        #pragma unroll
        for (int nt = 0; nt < 7; ++nt) {
            const bf16* wb = Wh + (nt * 16 + r16) * 128 + ks * 32 + kg * 8;
            bf16x8 bh = *(const bf16x8*)wb;
            bf16x8 bl = *(const bf16x8*)(wb + (Wl - Wh));
            acc[0][nt] = __builtin_amdgcn_mfma_f32_16x16x32_bf16(a0, bh, acc[0][nt], 0, 0, 0);
            acc[0][nt] = __builtin_amdgcn_mfma_f32_16x16x32_bf16(a0, bl, acc[0][nt], 0, 0, 0);
            acc[1][nt] = __builtin_amdgcn_mfma_f32_16x16x32_bf16(a1, bh, acc[1][nt], 0, 0, 0);
            acc[1][nt] = __builtin_amdgcn_mfma_f32_16x16x32_bf16(a1, bl, acc[1][nt], 0, 0, 0);
        }
    }

    #pragma unroll
    for (int rt = 0; rt < 2; ++rt) {
        #pragma unroll
        for (int nt = 0; nt < 7; ++nt) {
            int col = nt * 16 + r16;
            if (col >= D) continue;
            #pragma unroll
            for (int r = 0; r < 4; ++r) {
                long long row = m0 + rt * 16 + kg * 4 + r;
                if (row >= n) continue;
                float v = acc[rt][nt][r];
                if (mode == 1) {
                    v += __bfloat162float(X[row * XS + col]);
                    v = fmaxf(v, 0.f);
                }
                Y[row * XS + col] = __float2bfloat16(v);
            }
        }
    }
}

// ---------- CSR construction (one-time; edge structure constant across layers) ----------

__global__ void hist(const int* __restrict__ rows, const int* __restrict__ cols,
    int* __restrict__ cnt, int n, int nnz)
{
    int e = blockIdx.x * 256 + threadIdx.x;
    if (e >= nnz) return;
    int r = rows[e], c = cols[e];
    if ((unsigned)r >= (unsigned)n || (unsigned)c >= (unsigned)n) return;
    atomicAdd(&cnt[r], 1);
}

__global__ void scan1(const int* __restrict__ cnt, int* __restrict__ offs,
    int* __restrict__ bsum, int n)
{
    __shared__ int sh[256];
    int b = blockIdx.x, t = threadIdx.x;
    int base = b * 2048 + t * 8;
    int v[8];
    int s = 0;
    #pragma unroll
    for (int i = 0; i < 8; ++i) {
        int idx = base + i;
        v[i] = (idx < n) ? cnt[idx] : 0;
        s += v[i];
    }
    sh[t] = s; __syncthreads();
    for (int off = 1; off < 256; off <<= 1) {
        int x = (t >= off) ? sh[t - off] : 0;
        __syncthreads();
        sh[t] += x;
        __syncthreads();
    }
    int run = sh[t] - s;
    #pragma unroll
    for (int i = 0; i < 8; ++i) {
        run += v[i];
        int idx = base + i;
        if (idx < n) offs[idx + 1] = run;
    }
    if (t == 255) bsum[b] = sh[255];
}

__global__ void scan2(int* __restrict__ bsum, int nb)
{
    __shared__ int sh[256];
    int t = threadIdx.x;
    int v = (t < nb) ? bsum[t] : 0;
    sh[t] = v; __syncthreads();
    for (int off = 1; off < 256; off <<= 1) {
        int x = (t >= off) ? sh[t - off] : 0;
        __syncthreads();
        sh[t] += x;
        __syncthreads();
    }
    if (t < nb) bsum[t] = sh[t] - v;
}

__global__ void scan3(int* __restrict__ offs, const int* __restrict__ bsum, int n)
{
    int i = blockIdx.x * 256 + threadIdx.x;
    if (i == 0) offs[0] = 0;
    if (i < n) offs[i + 1] += bsum[i >> 11];
}

__global__ void scatter(const int* __restrict__ rows, const int* __restrict__ cols,
    const void* __restrict__ vals, const int* __restrict__ flag,
    const int* __restrict__ offs, int* __restrict__ fill, int2* __restrict__ ecv,
    int n, int nnz)
{
    int e = blockIdx.x * 256 + threadIdx.x;
    if (e >= nnz) return;
    int r = rows[e], c = cols[e];
    if ((unsigned)r >= (unsigned)n || (unsigned)c >= (unsigned)n) return;
    int pos = offs[r] + atomicAdd(&fill[r], 1);
    float v = ldf(vals, e, *flag);
    ecv[pos] = make_int2(c, __float_as_int(v));
}

// ---------- CSR SpMM: one wave per row, no atomics, full D in one pass ----------

__global__ void spmm_csr(const int* __restrict__ offs, const int2* __restrict__ ecv,
    const bf16* __restrict__ X, bf16* __restrict__ Y, int n)
{
    int wid = (int)(((long long)blockIdx.x * 256 + threadIdx.x) >> 6);
    int lane = threadIdx.x & 63;
    if (wid >= n) return;
    int s = offs[wid], e = offs[wid + 1];
    int d0 = lane * 2;
    if (d0 >= D) return;
    float a0 = 0.f, a1 = 0.f;
    int j = s;
    for (; j + 1 < e; j += 2) {
        int2 cv0 = ecv[j];
        int2 cv1 = ecv[j + 1];
        unsigned int u0 = *(const unsigned int*)(X + (long long)cv0.x * XS + d0);
        unsigned int u1 = *(const unsigned int*)(X + (long long)cv1.x * XS + d0);
        float v0 = __int_as_float(cv0.y);
        float v1 = __int_as_float(cv1.y);
        a0 = fmaf(v0, b2f((unsigned short)u0), a0);
        a1 = fmaf(v0, b2f((unsigned short)(u0 >> 16)), a1);
        a0 = fmaf(v1, b2f((unsigned short)u1), a0);
        a1 = fmaf(v1, b2f((unsigned short)(u1 >> 16)), a1);
    }
    if (j < e) {
        int2 cv = ecv[j];
        unsigned int u = *(const unsigned int*)(X + (long long)cv.x * XS + d0);
        float v = __int_as_float(cv.y);
        a0 = fmaf(v, b2f((unsigned short)u), a0);
        a1 = fmaf(v, b2f((unsigned short)(u >> 16)), a1);
    }
    *(unsigned int*)(Y + (long long)wid * XS + d0) =
        ((unsigned int)f2bu(a1) << 16) | f2bu(a0);
}

// ---------- in-place row softmax on bf16 [n, XS] (cols 0..99) ----------

__global__ void softmax_rows(bf16* __restrict__ L, int n)
{
    __shared__ float red[128];
    __shared__ float m_s, s_s;
    int r = blockIdx.x;
    if (r >= n) return;
    int d = threadIdx.x;
    float x = (d < D) ? __bfloat162float(L[(long long)r * XS + d]) : -3.0e38f;
    red[d] = x; __syncthreads();
    for (int off = 64; off; off >>= 1) {
        if (d < off) red[d] = fmaxf(red[d], red[d + off]);
        __syncthreads();
    }
    if (d == 0) m_s = red[0];
    __syncthreads();
    float e = (d < D) ? __expf(x - m_s) : 0.0f;
    red[d] = e; __syncthreads();
    for (int off = 64; off; off >>= 1) {
        if (d < off) red[d] += red[d + off];
        __syncthreads();
    }
    if (d == 0) s_s = red[0];
    __syncthreads();
    if (d < D) L[(long long)r * XS + d] = __float2bfloat16(e / s_s);
}

// ---------- hsm[k,d] = sum_n H1[n,k] * X2[n,d]: per-block partials + reduce ----------

#define HSM_G 250
#define HSM_BATCH 32

__global__ void hsm_partial(const bf16* __restrict__ H1, const bf16* __restrict__ X2,
    float* __restrict__ partials, int n)
{
    __shared__ float sh[HSM_BATCH][D];   // H1 rows (k)
    __shared__ float sx[HSM_BATCH][D];   // X2 rows (d)
    const int t = threadIdx.x;
    const int tk = t / 10;               // 0..24 active (t < 250)
    const int td = t - tk * 10;          // 0..9

    float acc[4][10];
    #pragma unroll
    for (int i = 0; i < 4; ++i)
        #pragma unroll
        for (int j = 0; j < 10; ++j) acc[i][j] = 0.f;

    const int per = (n + HSM_G - 1) / HSM_G;
    const int s = blockIdx.x * per;
    int e = s + per; if (e > n) e = n;

    for (int base = s; base < e; base += HSM_BATCH) {
        int cnt = e - base; if (cnt > HSM_BATCH) cnt = HSM_BATCH;
        __syncthreads();
        for (int v = t; v < cnt * 25; v += 256) {
            int r = v / 25, c4 = v - (v / 25) * 25;
            ushort4 h4 = *(const ushort4*)(H1 + (long long)(base + r) * XS + 4 * c4);
            ushort4 x4 = *(const ushort4*)(X2 + (long long)(base + r) * XS + 4 * c4);
            sh[r][4 * c4 + 0] = b2f(h4.x);
            sh[r][4 * c4 + 1] = b2f(h4.y);
            sh[r][4 * c4 + 2] = b2f(h4.z);
            sh[r][4 * c4 + 3] = b2f(h4.w);
            sx[r][4 * c4 + 0] = b2f(x4.x);
            sx[r][4 * c4 + 1] = b2f(x4.y);
            sx[r][4 * c4 + 2] = b2f(x4.z);
            sx[r][4 * c4 + 3] = b2f(x4.w);
        }
        __syncthreads();
        if (t < 250) {
            #pragma unroll 8
            for (int r = 0; r < cnt; ++r) {
                float4 a = *(const float4*)&sh[r][tk * 4];
                float b[10];
                #pragma unroll
                for (int j = 0; j < 10; ++j) b[j] = sx[r][td * 10 + j];
                #pragma unroll
                for (int j = 0; j < 10; ++j) {
                    acc[0][j] = fmaf(a.x, b[j], acc[0][j]);
                    acc[1][j] = fmaf(a.y, b[j], acc[1][j]);
                    acc[2][j] = fmaf(a.z, b[j], acc[2][j]);
                    acc[3][j] = fmaf(a.w, b[j], acc[3][j]);
                }
            }
        }
    }

    if (t < 250) {
        float* out = partials + (long long)blockIdx.x * (D * D);
        #pragma unroll
        for (int i = 0; i < 4; ++i)
            #pragma unroll
            for (int j = 0; j < 10; ++j)
                out[(tk * 4 + i) * D + td * 10 + j] = acc[i][j];
    }
}

__global__ void hsm_reduce(const float* __restrict__ partials, float* __restrict__ hsm)
{
    int i = blockIdx.x * 256 + threadIdx.x;
    if (i >= D * D) return;
    float s0 = 0.f, s1 = 0.f;
    for (int b = 0; b < HSM_G; b += 2) {
        s0 += partials[(long long)b * (D * D) + i];
        s1 += partials[(long long)(b + 1) * (D * D) + i];
    }
    hsm[i] = s0 + s1;
}

// ---- finrow: x_new = hN + x2 (into X); o0 += l2n(x_new); o1 += l2n(hN) (fp32) ----

__global__ void finrow(const bf16* __restrict__ Hn, bf16* __restrict__ X,
    float* __restrict__ o0, float* __restrict__ o1, int n)
{
    __shared__ float red[128];
    __shared__ float ia_s, ib_s;
    int r = blockIdx.x;
    if (r >= n) return;
    int d = threadIdx.x;
    long long b = (long long)r * XS;
    long long bo = (long long)r * D;
    float hn = (d < D) ? __bfloat162float(Hn[b + d]) : 0.f;
    float x2 = (d < D) ? __bfloat162float(X[b + d]) : 0.f;
    float xn = hn + x2;
    red[d] = xn * xn; __syncthreads();
    for (int off = 64; off; off >>= 1) {
        if (d < off) red[d] += red[d + off];
        __syncthreads();
    }
    if (d == 0) ia_s = 1.0f / fmaxf(sqrtf(red[0]), 1e-12f);
    __syncthreads();
    red[d] = hn * hn; __syncthreads();
    for (int off = 64; off; off >>= 1) {
        if (d < off) red[d] += red[d + off];
        __syncthreads();
    }
    if (d == 0) ib_s = 1.0f / fmaxf(sqrtf(red[0]), 1e-12f);
    __syncthreads();
    if (d < D) {
        X[b + d] = __float2bfloat16(xn);
        o0[bo + d] += xn * ia_s;
        o1[bo + d] += hn * ib_s;
    }
}

// ---------- host ----------

extern "C" void kernel_launch(void* const* d_in, const int* in_sizes, int n_in,
                              void* d_out, int out_size, void* d_ws, size_t ws_size,
                              hipStream_t stream)
{
    const void* emb   = d_in[0];
    // d_in[1] = adj: cancels exactly in column-normalization (softmax rows sum to 1)
    const void* evals = d_in[2];
    const void* Wit   = d_in[3];
    const void* Wi1   = d_in[4];
    const void* Wi2   = d_in[5];
    const int* erows  = (const int*)d_in[6];
    const int* ecols  = (const int*)d_in[7];
    const int N   = in_sizes[0] / D;
    const int NNZ = in_sizes[2];
    const long long ND = (long long)N * D;
    const size_t NB = (size_t)N * XS * 2;   // padded activation buffer bytes

    float* o0 = (float*)d_out;      // item_embeddings accumulator (fp32 output!)
    float* o1 = o0 + ND;            // hs accumulator

    char* base = (char*)d_ws;
    size_t off = 0;
    auto alloc = [&](size_t bytes) -> void* {
        void* r = base + off;
        off += (bytes + 255) & ~(size_t)255;
        return r;
    };
    int*   flag  = (int*)  alloc(256);
    float* hsm   = (float*)alloc(D * D * 4);
    bf16*  WH    = (bf16*) alloc(5 * 112 * 128 * 2);
    bf16*  WL    = (bf16*) alloc(5 * 112 * 128 * 2);
    bf16*  hsmTh = (bf16*) alloc(112 * 128 * 2);
    bf16*  hsmTl = (bf16*) alloc(112 * 128 * 2);
    int*   offs  = (int*)  alloc(((size_t)N + 1) * 4);
    int*   cnt   = (int*)  alloc((size_t)N * 4);        // reused as scatter fill
    int*   bsum  = (int*)  alloc(1024);
    int2*  ecv   = (int2*) alloc((size_t)NNZ * 8);
    bf16*  B1    = (bf16*) alloc(NB);
    bf16*  B2    = (bf16*) alloc(NB);
    bf16*  H1    = (bf16*) alloc(NB);
    float* partials = (float*)alloc((size_t)HSM_G * D * D * 4);

    const int gND = (int)((ND + 255) / 256);
    const int gE  = (NNZ + 255) / 256;
    const int nb  = (N + 2047) / 2048;
    const int gM  = (N + 127) / 128;          // gemm_mfma blocks (128 rows each)
    const int gS  = (N + 3) / 4;              // spmm: 4 waves per block

    detectk<<<1, 256, 0, stream>>>(emb, flag);
    wprep<<<(5 * 112 * 128 + 255) / 256, 256, 0, stream>>>(Wit, Wi1, Wi2, flag, WH, WL);
    // zero activation buffers once: pad cols (100..127) must be exact 0 for MFMA
    hipMemsetAsync(B1, 0, NB, stream);
    hipMemsetAsync(B2, 0, NB, stream);
    hipMemsetAsync(H1, 0, NB, stream);
    initk<<<gND, 256, 0, stream>>>(emb, flag, B1, o0, o1, (int)ND);

    // ---- one-time CSR build ----
    hipMemsetAsync(cnt, 0, (size_t)N * 4, stream);
    hist<<<gE, 256, 0, stream>>>(erows, ecols, cnt, N, NNZ);
    scan1<<<nb, 256, 0, stream>>>(cnt, offs, bsum, N);
    scan2<<<1, 256, 0, stream>>>(bsum, nb);
    scan3<<<(N + 255) / 256, 256, 0, stream>>>(offs, bsum, N);
    hipMemsetAsync(cnt, 0, (size_t)N * 4, stream);
    scatter<<<gE, 256, 0, stream>>>(erows, ecols, evals, flag, offs, cnt, ecv, N, NNZ);

    for (int l = 0; l < 3; ++l) {
        gemm_mfma<<<gM, 256, 0, stream>>>(B1, WH + l * 14336, WL + l * 14336,
                                          B2, N, 0);                 // B2 = x@W
        spmm_csr<<<gS, 256, 0, stream>>>(offs, ecv, B2, B1, N);      // B1 = A@B2
        gemm_mfma<<<gM, 256, 0, stream>>>(B1, WH + 3 * 14336, WL + 3 * 14336,
                                          B2, N, 1);                 // B2 = relu(x2@W1+x2)
        gemm_mfma<<<gM, 256, 0, stream>>>(B2, WH + 4 * 14336, WL + 4 * 14336,
                                          H1, N, 0);                 // H1 = logits
        softmax_rows<<<N, 128, 0, stream>>>(H1, N);                  // H1 = softmax
        hsm_partial<<<HSM_G, 256, 0, stream>>>(H1, B1, partials, N);
        hsm_reduce<<<(D * D + 255) / 256, 256, 0, stream>>>(partials, hsm);
        hsm_conv<<<(112 * 128 + 255) / 256, 256, 0, stream>>>(hsm, hsmTh, hsmTl);
        gemm_mfma<<<gM, 256, 0, stream>>>(H1, hsmTh, hsmTl, B2, N, 0); // B2 = hN
        finrow<<<N, 128, 0, stream>>>(B2, B1, o0, o1, N);            // B1 = x_new; accum
    }
    fink<<<gND, 256, 0, stream>>>(o0, o1, (int)ND);
}

// Round 5
// 1389.469 us; speedup vs baseline: 5.7958x; 1.2307x over previous
//
#include <hip/hip_runtime.h>
#include <hip/hip_bf16.h>

#define D 100
#define XS 128   // padded row stride (elements) for all activation buffers

typedef __hip_bfloat16 bf16;
typedef __attribute__((ext_vector_type(8))) short bf16x8;
typedef __attribute__((ext_vector_type(4))) float f32x4;

__device__ __forceinline__ float ldf(const void* p, long long i, int f32) {
    return f32 ? ((const float*)p)[i] : __bfloat162float(((const bf16*)p)[i]);
}

__device__ __forceinline__ float b2f(unsigned short u) {
    return __uint_as_float(((unsigned int)u) << 16);
}

__device__ __forceinline__ unsigned short f2bu(float x) {
    union { bf16 b; unsigned short u; } cv;
    cv.b = __float2bfloat16(x);
    return cv.u;
}

// ---------- input dtype detector: 0 = bf16, 1 = fp32 ----------
__global__ void detectk(const void* __restrict__ emb, int* __restrict__ flag)
{
    const unsigned short* u = (const unsigned short*)emb;
    __shared__ int cnt;
    if (threadIdx.x == 0) cnt = 0;
    __syncthreads();
    int good = 0;
    for (int i = threadIdx.x; i < 512; i += 256) {
        int e = (u[i] >> 7) & 0xFF;
        if (e >= 118 && e <= 137) good++;
    }
    atomicAdd(&cnt, good);
    __syncthreads();
    if (threadIdx.x == 0) *flag = (cnt >= 410) ? 0 : 1;
}

// ---------- weight prep: 5 matrices -> transposed, padded [112][128], hi/lo bf16 ----
// Wt[c][k] = W[k][c]; hi = bf16(w), lo = bf16(w - hi). Pad region = 0 exactly,
// so MFMA outputs for cols 100..111 are exact zeros (pad-invariant trick).

__global__ void wprep(const void* __restrict__ wi, const void* __restrict__ w1,
    const void* __restrict__ w2, const int* __restrict__ flag,
    bf16* __restrict__ wh, bf16* __restrict__ wl)
{
    int i = blockIdx.x * 256 + threadIdx.x;
    if (i >= 5 * 112 * 128) return;
    int m = i / (112 * 128), rem = i - m * (112 * 128);
    int c = rem / 128, k = rem - c * 128;
    float w = 0.f;
    if (c < D && k < D) {
        int f = *flag;
        long long si = (long long)k * D + c;
        if (m < 3)       w = ldf(wi, m * 10000 + si, f);
        else if (m == 3) w = ldf(w1, si, f);
        else             w = ldf(w2, si, f);
    }
    bf16 hb = __float2bfloat16(w);
    wh[i] = hb;
    wl[i] = __float2bfloat16(w - __bfloat162float(hb));
}

// ---------- per-layer hsm (fp32 [100][100]) -> transposed padded hi/lo ----------

__global__ void hsm_conv(const float* __restrict__ hsm, bf16* __restrict__ hh,
    bf16* __restrict__ hl)
{
    int i = blockIdx.x * 256 + threadIdx.x;
    if (i >= 112 * 128) return;
    int c = i / 128, k = i - c * 128;
    float w = (c < D && k < D) ? hsm[k * D + c] : 0.f;
    bf16 hb = __float2bfloat16(w);
    hh[i] = hb;
    hl[i] = __float2bfloat16(w - __bfloat162float(hb));
}

// initk: writes FULL padded rows (pads = 0) -> no big memsets needed anywhere.
__global__ void initk(const void* __restrict__ emb, const int* __restrict__ flag,
    bf16* __restrict__ x, float* __restrict__ o0, float* __restrict__ o1, int n)
{
    long long i = (long long)blockIdx.x * 256 + threadIdx.x;
    if (i >= (long long)n * XS) return;
    int nn = (int)(i >> 7), d = (int)(i & 127);
    float v = 0.f;
    if (d < D) v = ldf(emb, (long long)nn * D + d, *flag);
    x[i] = __float2bfloat16(v);
    if (d < D) {
        o0[(long long)nn * D + d] = v;   // final[0] = raw embedding (/4 in fink)
        o1[(long long)nn * D + d] = 0.0f;
    }
}

__global__ void fink(float* __restrict__ o0, float* __restrict__ o1, int nd)
{
    int i = blockIdx.x * 256 + threadIdx.x;
    if (i < nd) {
        o0[i] *= 0.25f;             // /(L+1)
        o1[i] *= (1.0f / 3.0f);     // /L
    }
}

// ---------- MFMA GEMM with fused epilogues ----------
// W given as transposed padded hi/lo bf16 [112][128].
// MODE 0: Y = X@W
// MODE 1: Y = relu(X@W + X)            (residual from A-input)
// MODE 2: Y = row_softmax(X@W)         (fp32 logits in-reg; shfl row-reduce)
// MODE 3: hn = X@W; xn = hn + X2; Y(=X2, in-place) = xn;
//         o0 += xn/||xn||; o1 += hn/||hn||    (fused finrow)
// 4 waves/block; wave owns 32 rows x 112 cols: acc[2 rt][7 nt].
// A-frag: row = lane&15, k = (lane>>4)*8 + j. C/D: col = lane&15,
// row = (lane>>4)*4 + reg [measured m89/m91].
// Row values live in 16 lanes (r16) x 7 regs of one wave -> shfl_xor 1/2/4/8
// reduces within the r16 group (kg bits 4..5 untouched).
// Cols 100..111 of every output are exact 0 (zero-padded W); cols 112..127
// zeroed explicitly -> pad invariant holds for all activation buffers.

template<int MODE>
__global__ __launch_bounds__(256) void gemm_mfma(
    const bf16* __restrict__ X, const bf16* __restrict__ Wh,
    const bf16* __restrict__ Wl, bf16* __restrict__ Y, int n,
    const bf16* __restrict__ X2, float* __restrict__ o0, float* __restrict__ o1)
{
    const int wave = threadIdx.x >> 6;
    const int lane = threadIdx.x & 63;
    const int r16 = lane & 15, kg = lane >> 4;
    const long long m0 = ((long long)blockIdx.x * 4 + wave) * 32;

    f32x4 acc[2][7];
    #pragma unroll
    for (int i = 0; i < 2; ++i)
        #pragma unroll
        for (int j = 0; j < 7; ++j) acc[i][j] = (f32x4){0.f, 0.f, 0.f, 0.f};

    const bf16* xa = X + (m0 + r16) * XS + kg * 8;
    #pragma unroll
    for (int ks = 0; ks < 4; ++ks) {
        bf16x8 a0 = *(const bf16x8*)(xa + ks * 32);
        bf16x8 a1 = *(const bf16x8*)(xa + 16 * XS + ks * 32);
        #pragma unroll
        for (int nt = 0; nt < 7; ++nt) {
            const bf16* wb = Wh + (nt * 16 + r16) * 128 + ks * 32 + kg * 8;
            bf16x8 bh = *(const bf16x8*)wb;
            bf16x8 bl = *(const bf16x8*)(wb + (Wl - Wh));
            acc[0][nt] = __builtin_amdgcn_mfma_f32_16x16x32_bf16(a0, bh, acc[0][nt], 0, 0, 0);
            acc[0][nt] = __builtin_amdgcn_mfma_f32_16x16x32_bf16(a0, bl, acc[0][nt], 0, 0, 0);
            acc[1][nt] = __builtin_amdgcn_mfma_f32_16x16x32_bf16(a1, bh, acc[1][nt], 0, 0, 0);
            acc[1][nt] = __builtin_amdgcn_mfma_f32_16x16x32_bf16(a1, bl, acc[1][nt], 0, 0, 0);
        }
    }

    if (MODE == 0 || MODE == 1) {
        #pragma unroll
        for (int rt = 0; rt < 2; ++rt)
            #pragma unroll
            for (int nt = 0; nt < 7; ++nt) {
                int col = nt * 16 + r16;
                #pragma unroll
                for (int r = 0; r < 4; ++r) {
                    long long row = m0 + rt * 16 + kg * 4 + r;
                    if (row >= n) continue;
                    float v = acc[rt][nt][r];
                    if (MODE == 1) {
                        v += __bfloat162float(X[row * XS + col]);
                        v = fmaxf(v, 0.f);
                    }
                    Y[row * XS + col] = __float2bfloat16(v);
                }
            }
    } else if (MODE == 2) {
        const bool v6 = (r16 < 4);                 // nt=6 valid cols: 96..99
        #pragma unroll
        for (int rt = 0; rt < 2; ++rt)
            #pragma unroll
            for (int r = 0; r < 4; ++r) {
                float m = -3.0e38f;
                #pragma unroll
                for (int nt = 0; nt < 7; ++nt)
                    if (nt < 6 || v6) m = fmaxf(m, acc[rt][nt][r]);
                m = fmaxf(m, __shfl_xor(m, 1));
                m = fmaxf(m, __shfl_xor(m, 2));
                m = fmaxf(m, __shfl_xor(m, 4));
                m = fmaxf(m, __shfl_xor(m, 8));
                float ex[7]; float s = 0.f;
                #pragma unroll
                for (int nt = 0; nt < 7; ++nt) {
                    ex[nt] = (nt < 6 || v6) ? __expf(acc[rt][nt][r] - m) : 0.f;
                    s += ex[nt];
                }
                s += __shfl_xor(s, 1);
                s += __shfl_xor(s, 2);
                s += __shfl_xor(s, 4);
                s += __shfl_xor(s, 8);
                float inv = 1.f / s;
                long long row = m0 + rt * 16 + kg * 4 + r;
                if (row < n) {
                    #pragma unroll
                    for (int nt = 0; nt < 7; ++nt)
                        Y[row * XS + nt * 16 + r16] = __float2bfloat16(ex[nt] * inv);
                }
            }
    } else {   // MODE == 3: fused finrow
        #pragma unroll
        for (int rt = 0; rt < 2; ++rt)
            #pragma unroll
            for (int r = 0; r < 4; ++r) {
                long long row = m0 + rt * 16 + kg * 4 + r;
                float xn[7], hn[7];
                float sx = 0.f, sh2 = 0.f;
                #pragma unroll
                for (int nt = 0; nt < 7; ++nt) {
                    int col = nt * 16 + r16;
                    float h = acc[rt][nt][r];
                    float x2v = __bfloat162float(X2[row * XS + col]);
                    float xv = h + x2v;
                    xn[nt] = xv; hn[nt] = h;
                    sx += xv * xv; sh2 += h * h;    // pad cols contribute 0 exactly
                }
                sx  += __shfl_xor(sx, 1);  sx  += __shfl_xor(sx, 2);
                sx  += __shfl_xor(sx, 4);  sx  += __shfl_xor(sx, 8);
                sh2 += __shfl_xor(sh2, 1); sh2 += __shfl_xor(sh2, 2);
                sh2 += __shfl_xor(sh2, 4); sh2 += __shfl_xor(sh2, 8);
                float ia = 1.f / fmaxf(sqrtf(sx), 1e-12f);
                float ib = 1.f / fmaxf(sqrtf(sh2), 1e-12f);
                if (row < n) {
                    long long bo = row * D;
                    #pragma unroll
                    for (int nt = 0; nt < 7; ++nt) {
                        int col = nt * 16 + r16;
                        Y[row * XS + col] = __float2bfloat16(xn[nt]);
                        if (col < D) {
                            o0[bo + col] += xn[nt] * ia;
                            o1[bo + col] += hn[nt] * ib;
                        }
                    }
                }
            }
    }

    // zero pads cols 112..127 (16 bf16 = two 16B chunks; lane pairs cover 32 rows)
    {
        int rr = lane >> 1, half = lane & 1;
        long long row = m0 + rr;
        if (row < n)
            *(int4*)(Y + row * XS + 112 + half * 8) = make_int4(0, 0, 0, 0);
    }
}

// ---------- CSR construction (rebuilt per launch; workspace is re-poisoned) ----------

__global__ void hist(const int* __restrict__ rows, const int* __restrict__ cols,
    int* __restrict__ cnt, int n, int nnz)
{
    int e = blockIdx.x * 256 + threadIdx.x;
    if (e >= nnz) return;
    int r = rows[e], c = cols[e];
    if ((unsigned)r >= (unsigned)n || (unsigned)c >= (unsigned)n) return;
    atomicAdd(&cnt[r], 1);
}

__global__ void scan1(const int* __restrict__ cnt, int* __restrict__ offs,
    int* __restrict__ bsum, int n)
{
    __shared__ int sh[256];
    int b = blockIdx.x, t = threadIdx.x;
    int base = b * 2048 + t * 8;
    int v[8];
    int s = 0;
    #pragma unroll
    for (int i = 0; i < 8; ++i) {
        int idx = base + i;
        v[i] = (idx < n) ? cnt[idx] : 0;
        s += v[i];
    }
    sh[t] = s; __syncthreads();
    for (int off = 1; off < 256; off <<= 1) {
        int x = (t >= off) ? sh[t - off] : 0;
        __syncthreads();
        sh[t] += x;
        __syncthreads();
    }
    int run = sh[t] - s;
    #pragma unroll
    for (int i = 0; i < 8; ++i) {
        run += v[i];
        int idx = base + i;
        if (idx < n) offs[idx + 1] = run;
    }
    if (t == 255) bsum[b] = sh[255];
}

__global__ void scan2(int* __restrict__ bsum, int nb)
{
    __shared__ int sh[256];
    int t = threadIdx.x;
    int v = (t < nb) ? bsum[t] : 0;
    sh[t] = v; __syncthreads();
    for (int off = 1; off < 256; off <<= 1) {
        int x = (t >= off) ? sh[t - off] : 0;
        __syncthreads();
        sh[t] += x;
        __syncthreads();
    }
    if (t < nb) bsum[t] = sh[t] - v;
}

__global__ void scan3(int* __restrict__ offs, const int* __restrict__ bsum, int n)
{
    int i = blockIdx.x * 256 + threadIdx.x;
    if (i == 0) offs[0] = 0;
    if (i < n) offs[i + 1] += bsum[i >> 11];
}

__global__ void scatter(const int* __restrict__ rows, const int* __restrict__ cols,
    const void* __restrict__ vals, const int* __restrict__ flag,
    const int* __restrict__ offs, int* __restrict__ fill, int2* __restrict__ ecv,
    int n, int nnz)
{
    int e = blockIdx.x * 256 + threadIdx.x;
    if (e >= nnz) return;
    int r = rows[e], c = cols[e];
    if ((unsigned)r >= (unsigned)n || (unsigned)c >= (unsigned)n) return;
    int pos = offs[r] + atomicAdd(&fill[r], 1);
    float v = ldf(vals, e, *flag);
    ecv[pos] = make_int2(c, __float_as_int(v));
}

// ---------- CSR SpMM: one wave per row, no atomics; unroll-4 gather ILP ----------

__global__ void spmm_csr(const int* __restrict__ offs, const int2* __restrict__ ecv,
    const bf16* __restrict__ X, bf16* __restrict__ Y, int n)
{
    int wid = (int)(((long long)blockIdx.x * 256 + threadIdx.x) >> 6);
    int lane = threadIdx.x & 63;
    if (wid >= n) return;
    int s = offs[wid], e = offs[wid + 1];
    int d0 = lane * 2;
    if (d0 >= D) return;
    float a0 = 0.f, a1 = 0.f;
    int j = s;
    for (; j + 3 < e; j += 4) {     // 4 gathers in flight per wave
        int2 cv0 = ecv[j];
        int2 cv1 = ecv[j + 1];
        int2 cv2 = ecv[j + 2];
        int2 cv3 = ecv[j + 3];
        unsigned int u0 = *(const unsigned int*)(X + (long long)cv0.x * XS + d0);
        unsigned int u1 = *(const unsigned int*)(X + (long long)cv1.x * XS + d0);
        unsigned int u2 = *(const unsigned int*)(X + (long long)cv2.x * XS + d0);
        unsigned int u3 = *(const unsigned int*)(X + (long long)cv3.x * XS + d0);
        float v0 = __int_as_float(cv0.y), v1 = __int_as_float(cv1.y);
        float v2 = __int_as_float(cv2.y), v3 = __int_as_float(cv3.y);
        a0 = fmaf(v0, b2f((unsigned short)u0), a0);
        a1 = fmaf(v0, b2f((unsigned short)(u0 >> 16)), a1);
        a0 = fmaf(v1, b2f((unsigned short)u1), a0);
        a1 = fmaf(v1, b2f((unsigned short)(u1 >> 16)), a1);
        a0 = fmaf(v2, b2f((unsigned short)u2), a0);
        a1 = fmaf(v2, b2f((unsigned short)(u2 >> 16)), a1);
        a0 = fmaf(v3, b2f((unsigned short)u3), a0);
        a1 = fmaf(v3, b2f((unsigned short)(u3 >> 16)), a1);
    }
    for (; j < e; ++j) {
        int2 cv = ecv[j];
        unsigned int u = *(const unsigned int*)(X + (long long)cv.x * XS + d0);
        float v = __int_as_float(cv.y);
        a0 = fmaf(v, b2f((unsigned short)u), a0);
        a1 = fmaf(v, b2f((unsigned short)(u >> 16)), a1);
    }
    *(unsigned int*)(Y + (long long)wid * XS + d0) =
        ((unsigned int)f2bu(a1) << 16) | f2bu(a0);
}

// ---------- hsm[k,d] = sum_n H1[n,k] * X2[n,d]: per-block partials + reduce ----------

#define HSM_G 250
#define HSM_BATCH 32

__global__ void hsm_partial(const bf16* __restrict__ H1, const bf16* __restrict__ X2,
    float* __restrict__ partials, int n)
{
    __shared__ float sh[HSM_BATCH][D];   // H1 rows (k)
    __shared__ float sx[HSM_BATCH][D];   // X2 rows (d)
    const int t = threadIdx.x;
    const int tk = t / 10;               // 0..24 active (t < 250)
    const int td = t - tk * 10;          // 0..9

    float acc[4][10];
    #pragma unroll
    for (int i = 0; i < 4; ++i)
        #pragma unroll
        for (int j = 0; j < 10; ++j) acc[i][j] = 0.f;

    const int per = (n + HSM_G - 1) / HSM_G;
    const int s = blockIdx.x * per;
    int e = s + per; if (e > n) e = n;

    for (int base = s; base < e; base += HSM_BATCH) {
        int cnt = e - base; if (cnt > HSM_BATCH) cnt = HSM_BATCH;
        __syncthreads();
        for (int v = t; v < cnt * 25; v += 256) {
            int r = v / 25, c4 = v - (v / 25) * 25;
            ushort4 h4 = *(const ushort4*)(H1 + (long long)(base + r) * XS + 4 * c4);
            ushort4 x4 = *(const ushort4*)(X2 + (long long)(base + r) * XS + 4 * c4);
            sh[r][4 * c4 + 0] = b2f(h4.x);
            sh[r][4 * c4 + 1] = b2f(h4.y);
            sh[r][4 * c4 + 2] = b2f(h4.z);
            sh[r][4 * c4 + 3] = b2f(h4.w);
            sx[r][4 * c4 + 0] = b2f(x4.x);
            sx[r][4 * c4 + 1] = b2f(x4.y);
            sx[r][4 * c4 + 2] = b2f(x4.z);
            sx[r][4 * c4 + 3] = b2f(x4.w);
        }
        __syncthreads();
        if (t < 250) {
            #pragma unroll 8
            for (int r = 0; r < cnt; ++r) {
                float4 a = *(const float4*)&sh[r][tk * 4];
                float b[10];
                #pragma unroll
                for (int j = 0; j < 10; ++j) b[j] = sx[r][td * 10 + j];
                #pragma unroll
                for (int j = 0; j < 10; ++j) {
                    acc[0][j] = fmaf(a.x, b[j], acc[0][j]);
                    acc[1][j] = fmaf(a.y, b[j], acc[1][j]);
                    acc[2][j] = fmaf(a.z, b[j], acc[2][j]);
                    acc[3][j] = fmaf(a.w, b[j], acc[3][j]);
                }
            }
        }
    }

    if (t < 250) {
        float* out = partials + (long long)blockIdx.x * (D * D);
        #pragma unroll
        for (int i = 0; i < 4; ++i)
            #pragma unroll
            for (int j = 0; j < 10; ++j)
                out[(tk * 4 + i) * D + td * 10 + j] = acc[i][j];
    }
}

__global__ void hsm_reduce(const float* __restrict__ partials, float* __restrict__ hsm)
{
    int i = blockIdx.x * 256 + threadIdx.x;
    if (i >= D * D) return;
    float s0 = 0.f, s1 = 0.f;
    for (int b = 0; b < HSM_G; b += 2) {
        s0 += partials[(long long)b * (D * D) + i];
        s1 += partials[(long long)(b + 1) * (D * D) + i];
    }
    hsm[i] = s0 + s1;
}

// ---------- host ----------

extern "C" void kernel_launch(void* const* d_in, const int* in_sizes, int n_in,
                              void* d_out, int out_size, void* d_ws, size_t ws_size,
                              hipStream_t stream)
{
    const void* emb   = d_in[0];
    // d_in[1] = adj: cancels exactly in column-normalization (softmax rows sum to 1)
    const void* evals = d_in[2];
    const void* Wit   = d_in[3];
    const void* Wi1   = d_in[4];
    const void* Wi2   = d_in[5];
    const int* erows  = (const int*)d_in[6];
    const int* ecols  = (const int*)d_in[7];
    const int N   = in_sizes[0] / D;
    const int NNZ = in_sizes[2];
    const long long ND = (long long)N * D;
    const size_t NB = (size_t)N * XS * 2;   // padded activation buffer bytes

    float* o0 = (float*)d_out;      // item_embeddings accumulator (fp32 output!)
    float* o1 = o0 + ND;            // hs accumulator

    char* base = (char*)d_ws;
    size_t off = 0;
    auto alloc = [&](size_t bytes) -> void* {
        void* r = base + off;
        off += (bytes + 255) & ~(size_t)255;
        return r;
    };
    int*   flag  = (int*)  alloc(256);
    float* hsm   = (float*)alloc(D * D * 4);
    bf16*  WH    = (bf16*) alloc(5 * 112 * 128 * 2);
    bf16*  WL    = (bf16*) alloc(5 * 112 * 128 * 2);
    bf16*  hsmTh = (bf16*) alloc(112 * 128 * 2);
    bf16*  hsmTl = (bf16*) alloc(112 * 128 * 2);
    int*   offs  = (int*)  alloc(((size_t)N + 1) * 4);
    int*   cnt   = (int*)  alloc((size_t)N * 4);        // reused as scatter fill
    int*   bsum  = (int*)  alloc(1024);
    int2*  ecv   = (int2*) alloc((size_t)NNZ * 8);
    bf16*  B1    = (bf16*) alloc(NB);
    bf16*  B2    = (bf16*) alloc(NB);
    bf16*  H1    = (bf16*) alloc(NB);
    float* partials = (float*)alloc((size_t)HSM_G * D * D * 4);

    const int gND = (int)((ND + 255) / 256);
    const int gNX = (int)(((long long)N * XS + 255) / 256);
    const int gE  = (NNZ + 255) / 256;
    const int nb  = (N + 2047) / 2048;
    const int gM  = (N + 127) / 128;          // gemm_mfma blocks (128 rows each)
    const int gS  = (N + 3) / 4;              // spmm: 4 waves per block

    detectk<<<1, 256, 0, stream>>>(emb, flag);
    wprep<<<(5 * 112 * 128 + 255) / 256, 256, 0, stream>>>(Wit, Wi1, Wi2, flag, WH, WL);
    initk<<<gNX, 256, 0, stream>>>(emb, flag, B1, o0, o1, N);

    // ---- one-time CSR build ----
    hipMemsetAsync(cnt, 0, (size_t)N * 4, stream);
    hist<<<gE, 256, 0, stream>>>(erows, ecols, cnt, N, NNZ);
    scan1<<<nb, 256, 0, stream>>>(cnt, offs, bsum, N);
    scan2<<<1, 256, 0, stream>>>(bsum, nb);
    scan3<<<(N + 255) / 256, 256, 0, stream>>>(offs, bsum, N);
    hipMemsetAsync(cnt, 0, (size_t)N * 4, stream);
    scatter<<<gE, 256, 0, stream>>>(erows, ecols, evals, flag, offs, cnt, ecv, N, NNZ);

    for (int l = 0; l < 3; ++l) {
        gemm_mfma<0><<<gM, 256, 0, stream>>>(B1, WH + l * 14336, WL + l * 14336,
                                             B2, N, nullptr, nullptr, nullptr);
        spmm_csr<<<gS, 256, 0, stream>>>(offs, ecv, B2, B1, N);      // B1 = A@B2
        gemm_mfma<1><<<gM, 256, 0, stream>>>(B1, WH + 3 * 14336, WL + 3 * 14336,
                                             B2, N, nullptr, nullptr, nullptr);
        gemm_mfma<2><<<gM, 256, 0, stream>>>(B2, WH + 4 * 14336, WL + 4 * 14336,
                                             H1, N, nullptr, nullptr, nullptr);
        hsm_partial<<<HSM_G, 256, 0, stream>>>(H1, B1, partials, N);
        hsm_reduce<<<(D * D + 255) / 256, 256, 0, stream>>>(partials, hsm);
        hsm_conv<<<(112 * 128 + 255) / 256, 256, 0, stream>>>(hsm, hsmTh, hsmTl);
        gemm_mfma<3><<<gM, 256, 0, stream>>>(H1, hsmTh, hsmTl, B1, N, B1, o0, o1);
    }
    fink<<<gND, 256, 0, stream>>>(o0, o1, (int)ND);
}

// Round 6
// 1279.147 us; speedup vs baseline: 6.2956x; 1.0862x over previous
//
#include <hip/hip_runtime.h>
#include <hip/hip_bf16.h>

#define D 100
#define XS 128   // padded row stride (elements) for all activation buffers

typedef __hip_bfloat16 bf16;
typedef __attribute__((ext_vector_type(8))) short bf16x8;
typedef __attribute__((ext_vector_type(4))) float f32x4;

__device__ __forceinline__ float ldf(const void* p, long long i, int f32) {
    return f32 ? ((const float*)p)[i] : __bfloat162float(((const bf16*)p)[i]);
}

__device__ __forceinline__ float b2f(unsigned short u) {
    return __uint_as_float(((unsigned int)u) << 16);
}

__device__ __forceinline__ unsigned short f2bu(float x) {
    union { bf16 b; unsigned short u; } cv;
    cv.b = __float2bfloat16(x);
    return cv.u;
}

// ---------- input dtype detector: 0 = bf16, 1 = fp32 ----------
__global__ void detectk(const void* __restrict__ emb, int* __restrict__ flag)
{
    const unsigned short* u = (const unsigned short*)emb;
    __shared__ int cnt;
    if (threadIdx.x == 0) cnt = 0;
    __syncthreads();
    int good = 0;
    for (int i = threadIdx.x; i < 512; i += 256) {
        int e = (u[i] >> 7) & 0xFF;
        if (e >= 118 && e <= 137) good++;
    }
    atomicAdd(&cnt, good);
    __syncthreads();
    if (threadIdx.x == 0) *flag = (cnt >= 410) ? 0 : 1;
}

// ---------- weight prep: 5 matrices -> transposed, padded [112][128], hi/lo bf16 ----
// Wt[c][k] = W[k][c]; hi = bf16(w), lo = bf16(w - hi). Pad region = 0 exactly,
// so MFMA outputs for cols 100..111 are exact zeros (pad-invariant trick).

__global__ void wprep(const void* __restrict__ wi, const void* __restrict__ w1,
    const void* __restrict__ w2, const int* __restrict__ flag,
    bf16* __restrict__ wh, bf16* __restrict__ wl)
{
    int i = blockIdx.x * 256 + threadIdx.x;
    if (i >= 5 * 112 * 128) return;
    int m = i / (112 * 128), rem = i - m * (112 * 128);
    int c = rem / 128, k = rem - c * 128;
    float w = 0.f;
    if (c < D && k < D) {
        int f = *flag;
        long long si = (long long)k * D + c;
        if (m < 3)       w = ldf(wi, m * 10000 + si, f);
        else if (m == 3) w = ldf(w1, si, f);
        else             w = ldf(w2, si, f);
    }
    bf16 hb = __float2bfloat16(w);
    wh[i] = hb;
    wl[i] = __float2bfloat16(w - __bfloat162float(hb));
}

// ---------- per-layer hsm (fp32 [100][100]) -> transposed padded hi/lo ----------

__global__ void hsm_conv(const float* __restrict__ hsm, bf16* __restrict__ hh,
    bf16* __restrict__ hl)
{
    int i = blockIdx.x * 256 + threadIdx.x;
    if (i >= 112 * 128) return;
    int c = i / 128, k = i - c * 128;
    float w = (c < D && k < D) ? hsm[k * D + c] : 0.f;
    bf16 hb = __float2bfloat16(w);
    hh[i] = hb;
    hl[i] = __float2bfloat16(w - __bfloat162float(hb));
}

// initk: writes FULL padded rows (pads = 0) -> no big memsets needed anywhere.
// o0 gets the /(L+1) = 0.25 scale fused here (fink deleted).
__global__ void initk(const void* __restrict__ emb, const int* __restrict__ flag,
    bf16* __restrict__ x, float* __restrict__ o0, float* __restrict__ o1, int n)
{
    long long i = (long long)blockIdx.x * 256 + threadIdx.x;
    if (i >= (long long)n * XS) return;
    int nn = (int)(i >> 7), d = (int)(i & 127);
    float v = 0.f;
    if (d < D) v = ldf(emb, (long long)nn * D + d, *flag);
    x[i] = __float2bfloat16(v);
    if (d < D) {
        o0[(long long)nn * D + d] = v * 0.25f;
        o1[(long long)nn * D + d] = 0.0f;
    }
}

// ---------- MFMA GEMM with fused epilogues ----------
// W given as transposed padded hi/lo bf16 [112][128].
// MODE 0: Y = X@W
// MODE 1: Y = relu(X@W + X)            (residual from A-input)
// MODE 2: Y = row_softmax(X@W)         (fp32 logits in-reg; shfl row-reduce)
// MODE 3: hn = X@W; xn = hn + X2; Y(=X2, in-place) = xn;
//         o0 += 0.25*xn/||xn||; o1 += (1/3)*hn/||hn||   (fused finrow + scales)
// ONE wave per block, 64 rows per wave: acc[4 rt][7 nt] (112 VGPRs).
// Rationale (r5 counters/arith): with 32 rows/wave, 12500 waves each re-read
// the full 57 KB W from L2 = 700 MB/gemm = the bound; 64 rows/wave + 1-wave
// blocks cuts that 8x to 88 MB and doubles MFMA work per B-load.
// A-frag: row = lane&15, k = (lane>>4)*8 + j. C/D: col = lane&15,
// row = (lane>>4)*4 + reg [measured m89/m91].
// Row reduces (softmax / L2-norm) use shfl_xor 1/2/4/8 within the r16 group.
// Rows >= n read garbage A; MFMA keeps garbage in its own C row; stores guarded.
// Cols 100..111 of outputs are exact 0 (zero-padded W); cols 112..127 zeroed
// explicitly -> pad invariant holds for all activation buffers.

template<int MODE>
__global__ __launch_bounds__(64) void gemm_mfma(
    const bf16* __restrict__ X, const bf16* __restrict__ Wh,
    const bf16* __restrict__ Wl, bf16* __restrict__ Y, int n,
    const bf16* __restrict__ X2, float* __restrict__ o0, float* __restrict__ o1)
{
    const int lane = threadIdx.x;
    const int r16 = lane & 15, kg = lane >> 4;
    const long long m0 = (long long)blockIdx.x * 64;

    f32x4 acc[4][7];
    #pragma unroll
    for (int i = 0; i < 4; ++i)
        #pragma unroll
        for (int j = 0; j < 7; ++j) acc[i][j] = (f32x4){0.f, 0.f, 0.f, 0.f};

    const bf16* xa = X + (m0 + r16) * XS + kg * 8;
    #pragma unroll
    for (int ks = 0; ks < 4; ++ks) {
        bf16x8 a0 = *(const bf16x8*)(xa + ks * 32);
        bf16x8 a1 = *(const bf16x8*)(xa + 16 * XS + ks * 32);
        bf16x8 a2 = *(const bf16x8*)(xa + 32 * XS + ks * 32);
        bf16x8 a3 = *(const bf16x8*)(xa + 48 * XS + ks * 32);
        #pragma unroll
        for (int nt = 0; nt < 7; ++nt) {
            const bf16* wb = Wh + (nt * 16 + r16) * 128 + ks * 32 + kg * 8;
            bf16x8 bh = *(const bf16x8*)wb;
            bf16x8 bl = *(const bf16x8*)(wb + (Wl - Wh));
            acc[0][nt] = __builtin_amdgcn_mfma_f32_16x16x32_bf16(a0, bh, acc[0][nt], 0, 0, 0);
            acc[0][nt] = __builtin_amdgcn_mfma_f32_16x16x32_bf16(a0, bl, acc[0][nt], 0, 0, 0);
            acc[1][nt] = __builtin_amdgcn_mfma_f32_16x16x32_bf16(a1, bh, acc[1][nt], 0, 0, 0);
            acc[1][nt] = __builtin_amdgcn_mfma_f32_16x16x32_bf16(a1, bl, acc[1][nt], 0, 0, 0);
            acc[2][nt] = __builtin_amdgcn_mfma_f32_16x16x32_bf16(a2, bh, acc[2][nt], 0, 0, 0);
            acc[2][nt] = __builtin_amdgcn_mfma_f32_16x16x32_bf16(a2, bl, acc[2][nt], 0, 0, 0);
            acc[3][nt] = __builtin_amdgcn_mfma_f32_16x16x32_bf16(a3, bh, acc[3][nt], 0, 0, 0);
            acc[3][nt] = __builtin_amdgcn_mfma_f32_16x16x32_bf16(a3, bl, acc[3][nt], 0, 0, 0);
        }
    }

    if (MODE == 0 || MODE == 1) {
        #pragma unroll
        for (int rt = 0; rt < 4; ++rt)
            #pragma unroll
            for (int nt = 0; nt < 7; ++nt) {
                int col = nt * 16 + r16;
                #pragma unroll
                for (int r = 0; r < 4; ++r) {
                    long long row = m0 + rt * 16 + kg * 4 + r;
                    if (row >= n) continue;
                    float v = acc[rt][nt][r];
                    if (MODE == 1) {
                        v += __bfloat162float(X[row * XS + col]);
                        v = fmaxf(v, 0.f);
                    }
                    Y[row * XS + col] = __float2bfloat16(v);
                }
            }
    } else if (MODE == 2) {
        const bool v6 = (r16 < 4);                 // nt=6 valid cols: 96..99
        #pragma unroll
        for (int rt = 0; rt < 4; ++rt)
            #pragma unroll
            for (int r = 0; r < 4; ++r) {
                float m = -3.0e38f;
                #pragma unroll
                for (int nt = 0; nt < 7; ++nt)
                    if (nt < 6 || v6) m = fmaxf(m, acc[rt][nt][r]);
                m = fmaxf(m, __shfl_xor(m, 1));
                m = fmaxf(m, __shfl_xor(m, 2));
                m = fmaxf(m, __shfl_xor(m, 4));
                m = fmaxf(m, __shfl_xor(m, 8));
                float ex[7]; float s = 0.f;
                #pragma unroll
                for (int nt = 0; nt < 7; ++nt) {
                    ex[nt] = (nt < 6 || v6) ? __expf(acc[rt][nt][r] - m) : 0.f;
                    s += ex[nt];
                }
                s += __shfl_xor(s, 1);
                s += __shfl_xor(s, 2);
                s += __shfl_xor(s, 4);
                s += __shfl_xor(s, 8);
                float inv = 1.f / s;
                long long row = m0 + rt * 16 + kg * 4 + r;
                if (row < n) {
                    #pragma unroll
                    for (int nt = 0; nt < 7; ++nt)
                        Y[row * XS + nt * 16 + r16] = __float2bfloat16(ex[nt] * inv);
                }
            }
    } else {   // MODE == 3: fused finrow (+ output scales: 0.25 and 1/3)
        #pragma unroll
        for (int rt = 0; rt < 4; ++rt)
            #pragma unroll
            for (int r = 0; r < 4; ++r) {
                long long row = m0 + rt * 16 + kg * 4 + r;
                float xn[7], hn[7];
                float sx = 0.f, sh2 = 0.f;
                #pragma unroll
                for (int nt = 0; nt < 7; ++nt) {
                    int col = nt * 16 + r16;
                    float h = acc[rt][nt][r];
                    float x2v = __bfloat162float(X2[row * XS + col]);
                    float xv = h + x2v;
                    xn[nt] = xv; hn[nt] = h;
                    sx += xv * xv; sh2 += h * h;    // pad cols contribute 0 exactly
                }
                sx  += __shfl_xor(sx, 1);  sx  += __shfl_xor(sx, 2);
                sx  += __shfl_xor(sx, 4);  sx  += __shfl_xor(sx, 8);
                sh2 += __shfl_xor(sh2, 1); sh2 += __shfl_xor(sh2, 2);
                sh2 += __shfl_xor(sh2, 4); sh2 += __shfl_xor(sh2, 8);
                float ia = 0.25f        / fmaxf(sqrtf(sx), 1e-12f);
                float ib = (1.f / 3.f)  / fmaxf(sqrtf(sh2), 1e-12f);
                if (row < n) {
                    long long bo = row * D;
                    #pragma unroll
                    for (int nt = 0; nt < 7; ++nt) {
                        int col = nt * 16 + r16;
                        Y[row * XS + col] = __float2bfloat16(xn[nt]);
                        if (col < D) {
                            o0[bo + col] += xn[nt] * ia;
                            o1[bo + col] += hn[nt] * ib;
                        }
                    }
                }
            }
    }

    // zero pads cols 112..127 (16 bf16 = 32 B; one lane per row)
    {
        long long row = m0 + lane;
        if (row < n) {
            *(int4*)(Y + row * XS + 112) = make_int4(0, 0, 0, 0);
            *(int4*)(Y + row * XS + 120) = make_int4(0, 0, 0, 0);
        }
    }
}

// ---------- CSR construction (rebuilt per launch; workspace is re-poisoned) ----------

__global__ void hist(const int* __restrict__ rows, const int* __restrict__ cols,
    int* __restrict__ cnt, int n, int nnz)
{
    int e = blockIdx.x * 256 + threadIdx.x;
    if (e >= nnz) return;
    int r = rows[e], c = cols[e];
    if ((unsigned)r >= (unsigned)n || (unsigned)c >= (unsigned)n) return;
    atomicAdd(&cnt[r], 1);
}

__global__ void scan1(const int* __restrict__ cnt, int* __restrict__ offs,
    int* __restrict__ bsum, int n)
{
    __shared__ int sh[256];
    int b = blockIdx.x, t = threadIdx.x;
    int base = b * 2048 + t * 8;
    int v[8];
    int s = 0;
    #pragma unroll
    for (int i = 0; i < 8; ++i) {
        int idx = base + i;
        v[i] = (idx < n) ? cnt[idx] : 0;
        s += v[i];
    }
    sh[t] = s; __syncthreads();
    for (int off = 1; off < 256; off <<= 1) {
        int x = (t >= off) ? sh[t - off] : 0;
        __syncthreads();
        sh[t] += x;
        __syncthreads();
    }
    int run = sh[t] - s;
    #pragma unroll
    for (int i = 0; i < 8; ++i) {
        run += v[i];
        int idx = base + i;
        if (idx < n) offs[idx + 1] = run;
    }
    if (t == 255) bsum[b] = sh[255];
}

__global__ void scan2(int* __restrict__ bsum, int nb)
{
    __shared__ int sh[256];
    int t = threadIdx.x;
    int v = (t < nb) ? bsum[t] : 0;
    sh[t] = v; __syncthreads();
    for (int off = 1; off < 256; off <<= 1) {
        int x = (t >= off) ? sh[t - off] : 0;
        __syncthreads();
        sh[t] += x;
        __syncthreads();
    }
    if (t < nb) bsum[t] = sh[t] - v;
}

__global__ void scan3(int* __restrict__ offs, const int* __restrict__ bsum, int n)
{
    int i = blockIdx.x * 256 + threadIdx.x;
    if (i == 0) offs[0] = 0;
    if (i < n) offs[i + 1] += bsum[i >> 11];
}

__global__ void scatter(const int* __restrict__ rows, const int* __restrict__ cols,
    const void* __restrict__ vals, const int* __restrict__ flag,
    const int* __restrict__ offs, int* __restrict__ fill, int2* __restrict__ ecv,
    int n, int nnz)
{
    int e = blockIdx.x * 256 + threadIdx.x;
    if (e >= nnz) return;
    int r = rows[e], c = cols[e];
    if ((unsigned)r >= (unsigned)n || (unsigned)c >= (unsigned)n) return;
    int pos = offs[r] + atomicAdd(&fill[r], 1);
    float v = ldf(vals, e, *flag);
    ecv[pos] = make_int2(c, __float_as_int(v));
}

// ---------- CSR SpMM: one wave per row, no atomics; 8 gathers in flight ----------

__global__ void spmm_csr(const int* __restrict__ offs, const int2* __restrict__ ecv,
    const bf16* __restrict__ X, bf16* __restrict__ Y, int n)
{
    int wid = (int)(((long long)blockIdx.x * 256 + threadIdx.x) >> 6);
    int lane = threadIdx.x & 63;
    if (wid >= n) return;
    int s = offs[wid], e = offs[wid + 1];
    int d0 = lane * 2;
    if (d0 >= D) return;
    float a0 = 0.f, a1 = 0.f;
    int j = s;
    for (; j + 7 < e; j += 8) {
        int2 cv[8];
        unsigned int u[8];
        #pragma unroll
        for (int q = 0; q < 8; ++q) cv[q] = ecv[j + q];
        #pragma unroll
        for (int q = 0; q < 8; ++q)
            u[q] = *(const unsigned int*)(X + (long long)cv[q].x * XS + d0);
        #pragma unroll
        for (int q = 0; q < 8; ++q) {
            float v = __int_as_float(cv[q].y);
            a0 = fmaf(v, b2f((unsigned short)u[q]), a0);
            a1 = fmaf(v, b2f((unsigned short)(u[q] >> 16)), a1);
        }
    }
    for (; j < e; ++j) {
        int2 cv = ecv[j];
        unsigned int u = *(const unsigned int*)(X + (long long)cv.x * XS + d0);
        float v = __int_as_float(cv.y);
        a0 = fmaf(v, b2f((unsigned short)u), a0);
        a1 = fmaf(v, b2f((unsigned short)(u >> 16)), a1);
    }
    *(unsigned int*)(Y + (long long)wid * XS + d0) =
        ((unsigned int)f2bu(a1) << 16) | f2bu(a0);
}

// ---------- hsm[k,d] = sum_n H1[n,k] * X2[n,d]: per-block partials + reduce ----------
// HSM_G = 512 (r5 lesson: 250 blocks < 256 CUs left half the SIMDs idle).

#define HSM_G 512
#define HSM_BATCH 32

__global__ void hsm_partial(const bf16* __restrict__ H1, const bf16* __restrict__ X2,
    float* __restrict__ partials, int n)
{
    __shared__ float sh[HSM_BATCH][D];   // H1 rows (k)
    __shared__ float sx[HSM_BATCH][D];   // X2 rows (d)
    const int t = threadIdx.x;
    const int tk = t / 10;               // 0..24 active (t < 250)
    const int td = t - tk * 10;          // 0..9

    float acc[4][10];
    #pragma unroll
    for (int i = 0; i < 4; ++i)
        #pragma unroll
        for (int j = 0; j < 10; ++j) acc[i][j] = 0.f;

    const int per = (n + HSM_G - 1) / HSM_G;
    const int s = blockIdx.x * per;
    int e = s + per; if (e > n) e = n;

    for (int base = s; base < e; base += HSM_BATCH) {
        int cnt = e - base; if (cnt > HSM_BATCH) cnt = HSM_BATCH;
        __syncthreads();
        for (int v = t; v < cnt * 25; v += 256) {
            int r = v / 25, c4 = v - (v / 25) * 25;
            ushort4 h4 = *(const ushort4*)(H1 + (long long)(base + r) * XS + 4 * c4);
            ushort4 x4 = *(const ushort4*)(X2 + (long long)(base + r) * XS + 4 * c4);
            sh[r][4 * c4 + 0] = b2f(h4.x);
            sh[r][4 * c4 + 1] = b2f(h4.y);
            sh[r][4 * c4 + 2] = b2f(h4.z);
            sh[r][4 * c4 + 3] = b2f(h4.w);
            sx[r][4 * c4 + 0] = b2f(x4.x);
            sx[r][4 * c4 + 1] = b2f(x4.y);
            sx[r][4 * c4 + 2] = b2f(x4.z);
            sx[r][4 * c4 + 3] = b2f(x4.w);
        }
        __syncthreads();
        if (t < 250) {
            #pragma unroll 8
            for (int r = 0; r < cnt; ++r) {
                float4 a = *(const float4*)&sh[r][tk * 4];
                const float2* bp = (const float2*)&sx[r][td * 10];  // 8B-aligned
                float2 b0 = bp[0], b1 = bp[1], b2 = bp[2], b3 = bp[3], b4 = bp[4];
                float b[10] = {b0.x, b0.y, b1.x, b1.y, b2.x, b2.y, b3.x, b3.y, b4.x, b4.y};
                #pragma unroll
                for (int j = 0; j < 10; ++j) {
                    acc[0][j] = fmaf(a.x, b[j], acc[0][j]);
                    acc[1][j] = fmaf(a.y, b[j], acc[1][j]);
                    acc[2][j] = fmaf(a.z, b[j], acc[2][j]);
                    acc[3][j] = fmaf(a.w, b[j], acc[3][j]);
                }
            }
        }
    }

    if (t < 250) {
        float* out = partials + (long long)blockIdx.x * (D * D);
        #pragma unroll
        for (int i = 0; i < 4; ++i)
            #pragma unroll
            for (int j = 0; j < 10; ++j)
                out[(tk * 4 + i) * D + td * 10 + j] = acc[i][j];
    }
}

__global__ void hsm_reduce(const float* __restrict__ partials, float* __restrict__ hsm)
{
    int i = blockIdx.x * 256 + threadIdx.x;
    if (i >= D * D) return;
    float s0 = 0.f, s1 = 0.f;
    for (int b = 0; b < HSM_G; b += 2) {
        s0 += partials[(long long)b * (D * D) + i];
        s1 += partials[(long long)(b + 1) * (D * D) + i];
    }
    hsm[i] = s0 + s1;
}

// ---------- host ----------

extern "C" void kernel_launch(void* const* d_in, const int* in_sizes, int n_in,
                              void* d_out, int out_size, void* d_ws, size_t ws_size,
                              hipStream_t stream)
{
    const void* emb   = d_in[0];
    // d_in[1] = adj: cancels exactly in column-normalization (softmax rows sum to 1)
    const void* evals = d_in[2];
    const void* Wit   = d_in[3];
    const void* Wi1   = d_in[4];
    const void* Wi2   = d_in[5];
    const int* erows  = (const int*)d_in[6];
    const int* ecols  = (const int*)d_in[7];
    const int N   = in_sizes[0] / D;
    const int NNZ = in_sizes[2];
    const long long ND = (long long)N * D;
    const size_t NB = (size_t)N * XS * 2;   // padded activation buffer bytes

    float* o0 = (float*)d_out;      // item_embeddings accumulator (fp32 output!)
    float* o1 = o0 + ND;            // hs accumulator

    char* base = (char*)d_ws;
    size_t off = 0;
    auto alloc = [&](size_t bytes) -> void* {
        void* r = base + off;
        off += (bytes + 255) & ~(size_t)255;
        return r;
    };
    int*   flag  = (int*)  alloc(256);
    float* hsm   = (float*)alloc(D * D * 4);
    bf16*  WH    = (bf16*) alloc(5 * 112 * 128 * 2);
    bf16*  WL    = (bf16*) alloc(5 * 112 * 128 * 2);
    bf16*  hsmTh = (bf16*) alloc(112 * 128 * 2);
    bf16*  hsmTl = (bf16*) alloc(112 * 128 * 2);
    int*   offs  = (int*)  alloc(((size_t)N + 1) * 4);
    int*   cnt   = (int*)  alloc((size_t)N * 4);        // reused as scatter fill
    int*   bsum  = (int*)  alloc(1024);
    int2*  ecv   = (int2*) alloc((size_t)NNZ * 8);
    bf16*  B1    = (bf16*) alloc(NB);
    bf16*  B2    = (bf16*) alloc(NB);
    bf16*  H1    = (bf16*) alloc(NB);
    (void)alloc(64 * XS * 2);   // guard: 64-row A-tiles may read past last buffer
    // partials (512 * 40 KB = 20.5 MB) alias B2: B2 is dead from after gemm<2>
    // (its consumer) until the next layer's gemm<0> rewrites it.
    float* partials = (float*)B2;

    const int gND = (int)((ND + 255) / 256);
    const int gNX = (int)(((long long)N * XS + 255) / 256);
    const int gE  = (NNZ + 255) / 256;
    const int nb  = (N + 2047) / 2048;
    const int gM  = (N + 63) / 64;            // gemm_mfma: 1 wave / 64 rows per block
    const int gS  = (N + 3) / 4;              // spmm: 4 waves per block

    detectk<<<1, 256, 0, stream>>>(emb, flag);
    wprep<<<(5 * 112 * 128 + 255) / 256, 256, 0, stream>>>(Wit, Wi1, Wi2, flag, WH, WL);
    initk<<<gNX, 256, 0, stream>>>(emb, flag, B1, o0, o1, N);

    // ---- one-time CSR build ----
    hipMemsetAsync(cnt, 0, (size_t)N * 4, stream);
    hist<<<gE, 256, 0, stream>>>(erows, ecols, cnt, N, NNZ);
    scan1<<<nb, 256, 0, stream>>>(cnt, offs, bsum, N);
    scan2<<<1, 256, 0, stream>>>(bsum, nb);
    scan3<<<(N + 255) / 256, 256, 0, stream>>>(offs, bsum, N);
    hipMemsetAsync(cnt, 0, (size_t)N * 4, stream);
    scatter<<<gE, 256, 0, stream>>>(erows, ecols, evals, flag, offs, cnt, ecv, N, NNZ);

    for (int l = 0; l < 3; ++l) {
        gemm_mfma<0><<<gM, 64, 0, stream>>>(B1, WH + l * 14336, WL + l * 14336,
                                            B2, N, nullptr, nullptr, nullptr);
        spmm_csr<<<gS, 256, 0, stream>>>(offs, ecv, B2, B1, N);      // B1 = A@B2
        gemm_mfma<1><<<gM, 64, 0, stream>>>(B1, WH + 3 * 14336, WL + 3 * 14336,
                                            B2, N, nullptr, nullptr, nullptr);
        gemm_mfma<2><<<gM, 64, 0, stream>>>(B2, WH + 4 * 14336, WL + 4 * 14336,
                                            H1, N, nullptr, nullptr, nullptr);
        hsm_partial<<<HSM_G, 256, 0, stream>>>(H1, B1, partials, N); // partials=B2
        hsm_reduce<<<(D * D + 255) / 256, 256, 0, stream>>>(partials, hsm);
        hsm_conv<<<(112 * 128 + 255) / 256, 256, 0, stream>>>(hsm, hsmTh, hsmTl);
        gemm_mfma<3><<<gM, 64, 0, stream>>>(H1, hsmTh, hsmTl, B1, N, B1, o0, o1);
    }
}